// Round 5
// baseline (559.224 us; speedup 1.0000x reference)
//
#include <hip/hip_runtime.h>
#include <hip/hip_bf16.h>

// Problem sizes (fixed)
#define Nn 32768   // nodes
#define Ee 131072  // edges
#define Gg 128     // graphs
#define Dd 128

using bf16 = __hip_bfloat16;
__device__ __forceinline__ float b2f(bf16 v){ return __bfloat162float(v); }
__device__ __forceinline__ bf16  f2b(float v){ return __float2bfloat16(v); }
__device__ __forceinline__ unsigned short bf16bits(float v){
  union { bf16 b; unsigned short u; } cv; cv.b = f2b(v); return cv.u;
}
__device__ __forceinline__ unsigned int packxh(float xv, float hv){
  return ((unsigned int)bf16bits(hv) << 16) | (unsigned int)bf16bits(xv);
}
__device__ __forceinline__ float upk_x(unsigned int v){ return __uint_as_float(v << 16); }
__device__ __forceinline__ float upk_h(unsigned int v){ return __uint_as_float(v & 0xffff0000u); }

// K1: x = xf@Wa + ba; nm = softmax_c(x@Wsc); h = relu(x@Wb2c). Register-tiled
// (4x4 per thread), x & h packed bf16x2 into xh.
__global__ __launch_bounds__(256)
void k_atom(const float* __restrict__ xf, const float* __restrict__ Wa,
            const float* __restrict__ ba, const float* __restrict__ Wsc,
            const float* __restrict__ Wb2c,
            unsigned int* __restrict__ xh, float* __restrict__ nm) {
  __shared__ float sxf[32*64];   // 8 KB
  __shared__ float sx[32*128];   // 16 KB
  __shared__ float ss[32*8];
  int tid = threadIdx.x, n0 = blockIdx.x * 32;
  int ct = tid & 31, rt = tid >> 5;
  int c0 = ct*4, r0 = rt*4;
  for (int j = tid; j < 2048; j += 256) sxf[j] = xf[n0*64 + j];
  __syncthreads();
  float acc[4][4];
  #pragma unroll
  for (int i = 0; i < 4; ++i)
    #pragma unroll
    for (int j = 0; j < 4; ++j) acc[i][j] = ba[c0+j];
  for (int k = 0; k < 64; ++k) {
    float4 bv = *reinterpret_cast<const float4*>(&Wa[k*128 + c0]);
    #pragma unroll
    for (int i = 0; i < 4; ++i) {
      float a = sxf[(r0+i)*64 + k];
      acc[i][0] += a*bv.x; acc[i][1] += a*bv.y; acc[i][2] += a*bv.z; acc[i][3] += a*bv.w;
    }
  }
  #pragma unroll
  for (int i = 0; i < 4; ++i)
    #pragma unroll
    for (int j = 0; j < 4; ++j) sx[(r0+i)*128 + c0+j] = acc[i][j];
  __syncthreads();
  // scorer: one (node,col) per thread
  {
    int node = tid >> 3, col = tid & 7;
    float s = 0.f;
    for (int d = 0; d < 128; ++d) s += sx[node*128 + d] * Wsc[d*8 + col];
    ss[node*8 + col] = s;
  }
  __syncthreads();
  if (tid < 64) {
    int i = tid >> 1, k = tid & 1;
    float v0 = ss[i*8 + 0 + k], v1 = ss[i*8 + 2 + k], v2 = ss[i*8 + 4 + k], v3 = ss[i*8 + 6 + k];
    float mx = fmaxf(fmaxf(v0, v1), fmaxf(v2, v3));
    float e0 = expf(v0-mx), e1 = expf(v1-mx), e2 = expf(v2-mx), e3 = expf(v3-mx);
    float inv = 1.f / (e0+e1+e2+e3);
    int n = n0 + i;
    nm[0*Nn + n] = e0*inv; nm[1*Nn + n] = e1*inv;
    nm[2*Nn + n] = e2*inv; nm[3*Nn + n] = e3*inv;
    nm[4*Nn + n] = 0.f;  // overwritten below for k=1; placeholder avoided:
  }
  // (note: k loop above covers k=0 and k=1 via tid&1; the nm writes for k=1
  //  use rc = 4..7)
  if (tid < 64) {
    int i = tid >> 1, k = tid & 1;
    if (k == 1) {
      float v0 = ss[i*8 + 1], v1 = ss[i*8 + 3], v2 = ss[i*8 + 5], v3 = ss[i*8 + 7];
      float mx = fmaxf(fmaxf(v0, v1), fmaxf(v2, v3));
      float e0 = expf(v0-mx), e1 = expf(v1-mx), e2 = expf(v2-mx), e3 = expf(v3-mx);
      float inv = 1.f / (e0+e1+e2+e3);
      int n = n0 + i;
      nm[4*Nn + n] = e0*inv; nm[5*Nn + n] = e1*inv;
      nm[6*Nn + n] = e2*inv; nm[7*Nn + n] = e3*inv;
    }
  }
  // b2c GEMM (K=128) from sx; pack x,h
  float acc2[4][4];
  #pragma unroll
  for (int i = 0; i < 4; ++i)
    #pragma unroll
    for (int j = 0; j < 4; ++j) acc2[i][j] = 0.f;
  for (int k = 0; k < 128; ++k) {
    float4 bv = *reinterpret_cast<const float4*>(&Wb2c[k*128 + c0]);
    #pragma unroll
    for (int i = 0; i < 4; ++i) {
      float a = sx[(r0+i)*128 + k];
      acc2[i][0] += a*bv.x; acc2[i][1] += a*bv.y; acc2[i][2] += a*bv.z; acc2[i][3] += a*bv.w;
    }
  }
  #pragma unroll
  for (int i = 0; i < 4; ++i)
    #pragma unroll
    for (int j = 0; j < 4; ++j)
      xh[(n0+r0+i)*128 + c0+j] = packxh(acc[i][j], fmaxf(acc2[i][j], 0.f));
}

// K2: edge_emb = ea @ We -> bf16 (weights in 16 VGPRs)
__global__ __launch_bounds__(256)
void k_eev(const float* __restrict__ ea, const float* __restrict__ We,
           bf16* __restrict__ eev) {
  __shared__ float sea[128*16];  // 8 KB
  int t = threadIdx.x, d = t & 127, q = t >> 7;
  size_t e0 = (size_t)blockIdx.x * 128;
  float w[16];
  #pragma unroll
  for (int j = 0; j < 16; ++j) w[j] = We[j*128 + d];
  for (int j = t; j < 2048; j += 256) sea[j] = ea[e0*16 + j];
  __syncthreads();
  for (int le = q; le < 128; le += 2) {
    float s = 0.f;
    #pragma unroll
    for (int j = 0; j < 16; ++j) s += sea[le*16 + j] * w[j];
    eev[(e0 + le)*128 + d] = f2b(s);
  }
}

// K3: node pooling, grid (g, node-quarter): num += nm*h, abc += nm*x, den += nm
__global__ __launch_bounds__(256)
void k_nodepool(const unsigned int* __restrict__ xh, const float* __restrict__ nm,
                float* __restrict__ num, float* __restrict__ abc,
                float* __restrict__ den) {
  __shared__ float snm[512];  // 8 rc x 64 nodes
  int t = threadIdx.x, d = t & 127, q = t >> 7;
  int g = blockIdx.x >> 2, pq = blockIdx.x & 3;
  int nbase = g*256 + pq*64;
  for (int j = t; j < 512; j += 256) snm[j] = nm[(j>>6)*Nn + nbase + (j&63)];
  __syncthreads();
  float aH[4] = {0,0,0,0}, aX[4] = {0,0,0,0};
  for (int p = 0; p < 64; ++p) {
    unsigned int v = xh[(nbase+p)*128 + d];
    float xv = upk_x(v), hv = upk_h(v);
    #pragma unroll
    for (int c = 0; c < 4; ++c) {
      float w = snm[(q*4+c)*64 + p];
      aH[c] += w*hv; aX[c] += w*xv;
    }
  }
  #pragma unroll
  for (int c = 0; c < 4; ++c) {
    atomicAdd(&num[((q*4+c)*Gg+g)*128 + d], aH[c]);
    atomicAdd(&abc[((q*4+c)*Gg+g)*128 + d], aX[c]);
  }
  if (t < 8) {
    float s = 0.f;
    for (int p = 0; p < 64; ++p) s += snm[t*64 + p];
    atomicAdd(&den[t*Gg + g], s);
  }
}

// K4: edge aggregation, grid (g, dst-quarter):
//   aggbb[dst] = sum x[src]+eev   (LDS tile, exclusive rows, no global atomics)
//   num[rc,g]  += sum nm[src]*nm[dst]^2*(h[src]+eev)
__global__ __launch_bounds__(256)
void k_edge(const unsigned int* __restrict__ xh, const float* __restrict__ nm,
            const float* __restrict__ ea, const float* __restrict__ We,
            const int* __restrict__ ei, const bf16* __restrict__ eev,
            float* __restrict__ aggbb, float* __restrict__ num) {
  __shared__ float snm[2048];     // 8 KB
  __shared__ int   ssrc[1024], sdst[1024]; // 8 KB
  __shared__ float sagg[64*128];  // 32 KB
  int t = threadIdx.x, d = t & 127, q = t >> 7;
  int g = blockIdx.x >> 2, quar = blockIdx.x & 3;
  int base = g*256, qlo = quar*64, qhi = qlo + 64;
  float w[16];
  #pragma unroll
  for (int j = 0; j < 16; ++j) w[j] = We[j*128 + d];
  for (int j = t; j < 2048; j += 256) snm[j] = nm[(j>>8)*Nn + base + (j&255)];
  for (int j = t; j < 1024; j += 256) {
    ssrc[j] = ei[g*1024 + j] - base;
    sdst[j] = ei[Ee + g*1024 + j] - base;
  }
  for (int j = t; j < 8192; j += 256) sagg[j] = 0.f;
  __syncthreads();
  float acc[8] = {0,0,0,0,0,0,0,0};
  for (int e = q; e < 1024; e += 2) {     // q wave-uniform -> uniform branch
    int dl = sdst[e];
    if (dl < qlo || dl >= qhi) continue;
    int sl = ssrc[e];
    float ev;
    if (eev) {
      ev = b2f(eev[((size_t)g*1024 + e)*128 + d]);
    } else {
      const float4* eap = reinterpret_cast<const float4*>(ea + ((size_t)g*1024 + e)*16);
      float4 a0 = eap[0], a1 = eap[1], a2 = eap[2], a3 = eap[3];
      ev = a0.x*w[0] + a0.y*w[1] + a0.z*w[2] + a0.w*w[3]
         + a1.x*w[4] + a1.y*w[5] + a1.z*w[6] + a1.w*w[7]
         + a2.x*w[8] + a2.y*w[9] + a2.z*w[10]+ a2.w*w[11]
         + a3.x*w[12]+ a3.y*w[13]+ a3.z*w[14]+ a3.w*w[15];
    }
    unsigned int v = xh[(base+sl)*128 + d];
    atomicAdd(&sagg[(dl-qlo)*128 + d], upk_x(v) + ev);
    float hv = upk_h(v) + ev;
    #pragma unroll
    for (int rc = 0; rc < 8; ++rc) {
      float b = snm[rc*256 + dl];
      acc[rc] += snm[rc*256 + sl] * b * b * hv;
    }
  }
  __syncthreads();
  for (int rl = q; rl < 64; rl += 2)
    aggbb[(base + qlo + rl)*128 + d] = sagg[rl*128 + d];
  #pragma unroll
  for (int rc = 0; rc < 8; ++rc)
    atomicAdd(&num[(rc*Gg + g)*128 + d], acc[rc]);
}

// K5: centroid-pair weights Wcc per (r,g) + global max
__global__ __launch_bounds__(256)
void k_wcc(const float* __restrict__ nm, const int* __restrict__ ei,
           float* __restrict__ wcc, unsigned int* __restrict__ maxbits) {
  __shared__ float red[20];
  int tid = threadIdx.x, g = blockIdx.x;
  if (tid < 20) red[tid] = 0.f;
  __syncthreads();
  float w[20];
  #pragma unroll
  for (int i = 0; i < 20; ++i) w[i] = 0.f;
  for (int qq = 0; qq < 4; ++qq) {
    int e = g*1024 + tid*4 + qq;
    int s = ei[e], d = ei[Ee + e];
    #pragma unroll
    for (int r = 0; r < 2; ++r) {
      float ps0 = nm[(r*4+0)*Nn+s], ps1 = nm[(r*4+1)*Nn+s], ps2 = nm[(r*4+2)*Nn+s], ps3 = nm[(r*4+3)*Nn+s];
      float pt0 = nm[(r*4+0)*Nn+d], pt1 = nm[(r*4+1)*Nn+d], pt2 = nm[(r*4+2)*Nn+d], pt3 = nm[(r*4+3)*Nn+d];
      w[r*10+0] += ps0*pt1; w[r*10+1] += ps0*pt2; w[r*10+2] += ps0*pt3;
      w[r*10+3] += ps1*pt2; w[r*10+4] += ps1*pt3; w[r*10+5] += ps2*pt3;
      w[r*10+6] += ps0*pt0; w[r*10+7] += ps1*pt1; w[r*10+8] += ps2*pt2; w[r*10+9] += ps3*pt3;
    }
  }
  #pragma unroll
  for (int i = 0; i < 20; ++i) atomicAdd(&red[i], w[i]);
  __syncthreads();
  if (tid < 32) {
    int r = tid >> 4, ij = tid & 15, i = ij >> 2, j = ij & 3;
    float v;
    if (i == j) v = 0.5f * red[r*10 + 6 + i];
    else { int a = i < j ? i : j, b = i < j ? j : i;
           int p = (a == 0) ? (b - 1) : (a == 1) ? (b + 1) : 5;
           v = red[r*10 + p]; }
    wcc[(r*Gg + g)*16 + ij] = v;
    atomicMax(maxbits, __float_as_uint(v));
  }
}

// K6: IN-PLACE: aggbb <- aggbb@Wbb + x@Wsb. Register-tiled 8x4.
__global__ __launch_bounds__(256)
void k_bbsb(float* __restrict__ aggbb, const unsigned int* __restrict__ xh,
            const float* __restrict__ Wbb, const float* __restrict__ Wsb) {
  __shared__ float sa[64*128];          // 32 KB
  __shared__ unsigned int sxh[64*128];  // 32 KB
  int tid = threadIdx.x, n0 = blockIdx.x*64;
  int ct = tid & 31, rt = tid >> 5;
  int c0 = ct*4, r0 = rt*8;
  for (int j = tid; j < 8192; j += 256) { sa[j] = aggbb[n0*128 + j]; sxh[j] = xh[n0*128 + j]; }
  __syncthreads();
  float acc[8][4];
  #pragma unroll
  for (int i = 0; i < 8; ++i)
    #pragma unroll
    for (int j = 0; j < 4; ++j) acc[i][j] = 0.f;
  for (int k = 0; k < 128; ++k) {
    float4 w1 = *reinterpret_cast<const float4*>(&Wbb[k*128 + c0]);
    float4 w2 = *reinterpret_cast<const float4*>(&Wsb[k*128 + c0]);
    #pragma unroll
    for (int i = 0; i < 8; ++i) {
      float a1 = sa[(r0+i)*128 + k];
      float a2 = upk_x(sxh[(r0+i)*128 + k]);
      acc[i][0] += a1*w1.x + a2*w2.x; acc[i][1] += a1*w1.y + a2*w2.y;
      acc[i][2] += a1*w1.z + a2*w2.z; acc[i][3] += a1*w1.w + a2*w2.w;
    }
  }
  __syncthreads();
  #pragma unroll
  for (int i = 0; i < 8; ++i)
    #pragma unroll
    for (int j = 0; j < 4; ++j) aggbb[(n0+r0+i)*128 + c0+j] = acc[i][j];
}

// K7: cent_x = num/(den+1e-6); h_cent = relu(abc@Wbc + (Wcc_n@cent)@Wcc + cent@Wsc)
__global__ __launch_bounds__(128)
void k_hcent(const float* __restrict__ num, const float* __restrict__ den,
             const float* __restrict__ abc, const float* __restrict__ wcc,
             const unsigned int* __restrict__ maxbits,
             const float* __restrict__ Wbc, const float* __restrict__ Wcc_,
             const float* __restrict__ Wsc2, float* __restrict__ hcent) {
  __shared__ float scent[512], sbc[512], sccs[512], swcc[16];
  int tid = threadIdx.x, r = blockIdx.x >> 7, g = blockIdx.x & 127;
  float inv = 1.f / (__uint_as_float(*maxbits) + 1e-9f);
  if (tid < 16) swcc[tid] = wcc[(r*Gg + g)*16 + tid] * inv;
  for (int c = 0; c < 4; ++c) {
    int rc = r*4 + c;
    float dn = den[rc*Gg + g] + 1e-6f;
    scent[c*128 + tid] = num[(rc*Gg + g)*128 + tid] / dn;
    sbc[c*128 + tid]   = abc[(rc*Gg + g)*128 + tid];
  }
  __syncthreads();
  for (int i = 0; i < 4; ++i) {
    sccs[i*128 + tid] = swcc[i*4+0]*scent[tid]       + swcc[i*4+1]*scent[128 + tid]
                      + swcc[i*4+2]*scent[256 + tid] + swcc[i*4+3]*scent[384 + tid];
  }
  __syncthreads();
  for (int c = 0; c < 4; ++c) {
    float acc = 0.f;
    for (int k = 0; k < 128; ++k) {
      acc += sbc[c*128 + k]   * Wbc[k*128 + tid];
      acc += sccs[c*128 + k]  * Wcc_[k*128 + tid];
      acc += scent[c*128 + k] * Wsc2[k*128 + tid];
    }
    hcent[((r*Gg + g)*4 + c)*128 + tid] = fmaxf(acc, 0.f);
  }
}

// K8: agg_cb = sum_c nm*h_cent; h_base = relu(bbsb + agg_cb@Wcb);
// mean over r; per-graph sums into gsum. Register-tiled 8x4.
__global__ __launch_bounds__(256)
void k_hbase(const float* __restrict__ bbsb, const float* __restrict__ nm,
             const float* __restrict__ hcent, const float* __restrict__ Wcb,
             float* __restrict__ gsum) {
  __shared__ float scb[64*128];  // 32 KB
  __shared__ float shc[512];
  __shared__ float snm4[256];
  int tid = threadIdx.x, n0 = blockIdx.x*64, g = n0 >> 8;
  int ct = tid & 31, rt = tid >> 5;
  int c0 = ct*4, r0 = rt*8;
  float bb[8][4], msum[8][4];
  #pragma unroll
  for (int i = 0; i < 8; ++i) {
    float4 v = *reinterpret_cast<const float4*>(&bbsb[(n0+r0+i)*128 + c0]);
    bb[i][0]=v.x; bb[i][1]=v.y; bb[i][2]=v.z; bb[i][3]=v.w;
    msum[i][0]=msum[i][1]=msum[i][2]=msum[i][3]=0.f;
  }
  for (int r = 0; r < 2; ++r) {
    for (int j = tid; j < 512; j += 256) shc[j] = hcent[((r*Gg + g)*4)*128 + j];
    if (tid < 256) {
      int node = tid >> 2, c = tid & 3;
      snm4[tid] = nm[(r*4 + c)*Nn + n0 + node];
    }
    __syncthreads();
    for (int j = tid; j < 8192; j += 256) {
      int node = j >> 7, k = j & 127;
      scb[j] = snm4[node*4+0]*shc[k]       + snm4[node*4+1]*shc[128 + k]
             + snm4[node*4+2]*shc[256 + k] + snm4[node*4+3]*shc[384 + k];
    }
    __syncthreads();
    float acc[8][4];
    #pragma unroll
    for (int i = 0; i < 8; ++i)
      #pragma unroll
      for (int j = 0; j < 4; ++j) acc[i][j] = 0.f;
    for (int k = 0; k < 128; ++k) {
      float4 wv = *reinterpret_cast<const float4*>(&Wcb[k*128 + c0]);
      #pragma unroll
      for (int i = 0; i < 8; ++i) {
        float a = scb[(r0+i)*128 + k];
        acc[i][0] += a*wv.x; acc[i][1] += a*wv.y; acc[i][2] += a*wv.z; acc[i][3] += a*wv.w;
      }
    }
    #pragma unroll
    for (int i = 0; i < 8; ++i)
      #pragma unroll
      for (int j = 0; j < 4; ++j)
        msum[i][j] += 0.5f * fmaxf(bb[i][j] + acc[i][j], 0.f);
    __syncthreads();
  }
  #pragma unroll
  for (int j = 0; j < 4; ++j) {
    float tot = 0.f;
    #pragma unroll
    for (int i = 0; i < 8; ++i) tot += msum[i][j];
    atomicAdd(&gsum[g*128 + c0 + j], tot);
  }
}

// K9: graph mean + W_inter + W_out head
__global__ __launch_bounds__(128)
void k_out(const float* __restrict__ gsum, const float* __restrict__ Wint,
           const float* __restrict__ bint, const float* __restrict__ Wout,
           const float* __restrict__ bout, float* __restrict__ out) {
  __shared__ float ss[128], sge[128];
  int tid = threadIdx.x, g = blockIdx.x;
  ss[tid] = gsum[g*128 + tid] * (1.f/256.f);
  __syncthreads();
  float ge = bint[tid];
  for (int k = 0; k < 128; ++k) ge += ss[k] * Wint[k*128 + tid];
  sge[tid] = ge;
  __syncthreads();
  if (tid < 10) {
    float o = bout[tid];
    for (int d = 0; d < 128; ++d) o += sge[d] * Wout[d*10 + tid];
    out[g*10 + tid] = o;
  }
}

extern "C" void kernel_launch(void* const* d_in, const int* in_sizes, int n_in,
                              void* d_out, int out_size, void* d_ws, size_t ws_size,
                              hipStream_t stream) {
  const float* xf   = (const float*)d_in[0];
  const float* ea   = (const float*)d_in[1];
  const float* Wa   = (const float*)d_in[2];
  const float* ba   = (const float*)d_in[3];
  const float* Wsc  = (const float*)d_in[4];
  const float* We   = (const float*)d_in[5];
  const float* Wb2c = (const float*)d_in[6];
  const float* Wbb  = (const float*)d_in[7];
  const float* Wbc  = (const float*)d_in[8];
  const float* Wcb  = (const float*)d_in[9];
  const float* WccW = (const float*)d_in[10];
  const float* Wsb  = (const float*)d_in[11];
  const float* Wsc2 = (const float*)d_in[12];
  const float* Wint = (const float*)d_in[13];
  const float* bint = (const float*)d_in[14];
  const float* Wout = (const float*)d_in[15];
  const float* bout = (const float*)d_in[16];
  const int*   ei   = (const int*)d_in[17];

  // Workspace layout (float offsets)
  float* ws    = (float*)d_ws;
  unsigned int* xh = (unsigned int*)ws;              // [N,128] packed bf16x2 (4,194,304 f)
  float* nm    = ws + 4194304;                       // [8,N]       (262,144 f)
  float* hcent = ws + 4456448;                       // [R,G,4,128] (131,072 f)
  float* wcc   = ws + 4587520;                       // [R,G,16]    (4,096 f)
  float* aggbb = ws + 4591616;                       // [N,128] fp32 (4,194,304 f) -> bbsb in-place
  float* num   = ws + 8785920;                       // [8,G,128]   (131,072 f)
  float* abc   = ws + 8916992;                       // [8,G,128]   (131,072 f)
  float* den   = ws + 9048064;                       // [8,G]       (1,024 f)
  float* gsum  = ws + 9049088;                       // [G,128]     (16,384 f)
  unsigned int* maxbits = (unsigned int*)(ws + 9065472); // (64 f)
  bf16* eev    = (bf16*)(ws + 9065536);              // [E,128] bf16 (8,388,608 f) OPTIONAL
  bool useEEV  = ws_size >= (size_t)17454144 * 4;

  hipMemsetAsync(num, 0, (131072 + 131072 + 1024 + 16384 + 64) * sizeof(float), stream);

  k_atom    <<<Nn/32, 256, 0, stream>>>(xf, Wa, ba, Wsc, Wb2c, xh, nm);
  if (useEEV)
    k_eev   <<<Ee/128, 256, 0, stream>>>(ea, We, eev);
  k_nodepool<<<Gg*4, 256, 0, stream>>>(xh, nm, num, abc, den);
  k_edge    <<<Gg*4, 256, 0, stream>>>(xh, nm, ea, We, ei, useEEV ? eev : (bf16*)nullptr, aggbb, num);
  k_wcc     <<<Gg,   256, 0, stream>>>(nm, ei, wcc, maxbits);
  k_bbsb    <<<Nn/64,256, 0, stream>>>(aggbb, xh, Wbb, Wsb);
  k_hcent   <<<2*Gg, 128, 0, stream>>>(num, den, abc, wcc, maxbits, Wbc, WccW, Wsc2, hcent);
  k_hbase   <<<Nn/64,256, 0, stream>>>(aggbb, nm, hcent, Wcb, gsum);
  k_out     <<<Gg,   128, 0, stream>>>(gsum, Wint, bint, Wout, bout, (float*)d_out);
}

// Round 6
// 334.276 us; speedup vs baseline: 1.6729x; 1.6729x over previous
//
#include <hip/hip_runtime.h>
#include <hip/hip_bf16.h>

// Problem sizes (fixed)
#define Nn 32768   // nodes
#define Ee 131072  // edges
#define Gg 128     // graphs
#define Dd 128

using bf16 = __hip_bfloat16;
__device__ __forceinline__ float b2f(bf16 v){ return __bfloat162float(v); }
__device__ __forceinline__ bf16  f2b(float v){ return __float2bfloat16(v); }
__device__ __forceinline__ unsigned short bf16bits(float v){
  union { bf16 b; unsigned short u; } cv; cv.b = f2b(v); return cv.u;
}
__device__ __forceinline__ unsigned int packxh(float xv, float hv){
  return ((unsigned int)bf16bits(hv) << 16) | (unsigned int)bf16bits(xv);
}
__device__ __forceinline__ float upk_x(unsigned int v){ return __uint_as_float(v << 16); }
__device__ __forceinline__ float upk_h(unsigned int v){ return __uint_as_float(v & 0xffff0000u); }

// K1: x = xf@Wa + ba; nmt[n][rc] = softmax_c(x@Wsc); h = relu(x@Wb2c).
// Register-tiled 4x4; x,h packed bf16x2 into xh[N,128].
__global__ __launch_bounds__(256)
void k_atom(const float* __restrict__ xf, const float* __restrict__ Wa,
            const float* __restrict__ ba, const float* __restrict__ Wsc,
            const float* __restrict__ Wb2c,
            unsigned int* __restrict__ xh, float* __restrict__ nmt) {
  __shared__ float sxf[32*64];   // 8 KB
  __shared__ float sx[32*128];   // 16 KB
  __shared__ float ss[32*8];
  int tid = threadIdx.x, n0 = blockIdx.x * 32;
  int ct = tid & 31, rt = tid >> 5;
  int c0 = ct*4, r0 = rt*4;
  for (int j = tid; j < 2048; j += 256) sxf[j] = xf[n0*64 + j];
  __syncthreads();
  float acc[4][4];
  #pragma unroll
  for (int i = 0; i < 4; ++i)
    #pragma unroll
    for (int j = 0; j < 4; ++j) acc[i][j] = ba[c0+j];
  for (int k = 0; k < 64; ++k) {
    float4 bv = *reinterpret_cast<const float4*>(&Wa[k*128 + c0]);
    #pragma unroll
    for (int i = 0; i < 4; ++i) {
      float a = sxf[(r0+i)*64 + k];
      acc[i][0] += a*bv.x; acc[i][1] += a*bv.y; acc[i][2] += a*bv.z; acc[i][3] += a*bv.w;
    }
  }
  #pragma unroll
  for (int i = 0; i < 4; ++i)
    #pragma unroll
    for (int j = 0; j < 4; ++j) sx[(r0+i)*128 + c0+j] = acc[i][j];
  __syncthreads();
  // scorer: one (node,col) per thread; col = c*2 + k
  {
    int node = tid >> 3, col = tid & 7;
    float s = 0.f;
    for (int d = 0; d < 128; ++d) s += sx[node*128 + d] * Wsc[d*8 + col];
    ss[node*8 + col] = s;
  }
  __syncthreads();
  if (tid < 64) {
    int node = tid >> 1, k = tid & 1;
    float v0 = ss[node*8 + 0 + k], v1 = ss[node*8 + 2 + k];
    float v2 = ss[node*8 + 4 + k], v3 = ss[node*8 + 6 + k];
    float mx = fmaxf(fmaxf(v0, v1), fmaxf(v2, v3));
    float e0 = expf(v0-mx), e1 = expf(v1-mx), e2 = expf(v2-mx), e3 = expf(v3-mx);
    float inv = 1.f / (e0+e1+e2+e3);
    size_t nb = (size_t)(n0 + node)*8 + k*4;
    nmt[nb+0] = e0*inv; nmt[nb+1] = e1*inv; nmt[nb+2] = e2*inv; nmt[nb+3] = e3*inv;
  }
  // b2c GEMM from sx; pack x,h
  float acc2[4][4];
  #pragma unroll
  for (int i = 0; i < 4; ++i)
    #pragma unroll
    for (int j = 0; j < 4; ++j) acc2[i][j] = 0.f;
  for (int k = 0; k < 128; ++k) {
    float4 bv = *reinterpret_cast<const float4*>(&Wb2c[k*128 + c0]);
    #pragma unroll
    for (int i = 0; i < 4; ++i) {
      float a = sx[(r0+i)*128 + k];
      acc2[i][0] += a*bv.x; acc2[i][1] += a*bv.y; acc2[i][2] += a*bv.z; acc2[i][3] += a*bv.w;
    }
  }
  #pragma unroll
  for (int i = 0; i < 4; ++i)
    #pragma unroll
    for (int j = 0; j < 4; ++j)
      xh[(size_t)(n0+r0+i)*128 + c0+j] = packxh(acc[i][j], fmaxf(acc2[i][j], 0.f));
}

// K2: per-graph dst-CSR build (+ den = per-graph sum of nmt)
__global__ __launch_bounds__(256)
void k_csr(const int* __restrict__ ei, const float* __restrict__ nmt,
           int* __restrict__ order, int* __restrict__ osrc,
           int* __restrict__ rowstart, float* __restrict__ den) {
  __shared__ int cnt[256], off[256], sdl[1024];
  __shared__ float sden[256*8];
  int t = threadIdx.x, g = blockIdx.x;
  cnt[t] = 0;
  __syncthreads();
  #pragma unroll
  for (int j = 0; j < 4; ++j) {
    int e = t + j*256;
    int dl = ei[Ee + g*1024 + e] - g*256;
    sdl[e] = dl;
    atomicAdd(&cnt[dl], 1);
  }
  // den partials
  {
    const float4* p = reinterpret_cast<const float4*>(nmt + (size_t)(g*256 + t)*8);
    float4 a = p[0], b = p[1];
    sden[t*8+0]=a.x; sden[t*8+1]=a.y; sden[t*8+2]=a.z; sden[t*8+3]=a.w;
    sden[t*8+4]=b.x; sden[t*8+5]=b.y; sden[t*8+6]=b.z; sden[t*8+7]=b.w;
  }
  __syncthreads();
  // inclusive scan of cnt -> off
  off[t] = cnt[t];
  __syncthreads();
  for (int s = 1; s < 256; s <<= 1) {
    int v = (t >= s) ? off[t - s] : 0;
    __syncthreads();
    off[t] += v;
    __syncthreads();
  }
  int startv = off[t] - cnt[t];
  rowstart[g*256 + t] = startv;
  off[t] = startv;
  __syncthreads();
  #pragma unroll
  for (int j = 0; j < 4; ++j) {
    int e = t + j*256;
    int pos = atomicAdd(&off[sdl[e]], 1);
    order[g*1024 + pos] = e;
    osrc[g*1024 + pos]  = ei[g*1024 + e];  // global src id
  }
  if (t < 8) {
    float s = 0.f;
    for (int p = 0; p < 256; ++p) s += sden[p*8 + t];
    den[t*Gg + g] = s;
  }
}

// K3: dst-CSR gather. grid (g, eighth)=1024 blocks; thread (q,d).
//   aggbb[n,:] = sum_{e in(n)} x[src]+eev      (registers, direct store)
//   pnum/pabc partials per (rc, g, eighth*2+q)  (no atomics)
__global__ __launch_bounds__(256)
void k_gather(const unsigned int* __restrict__ xh, const float* __restrict__ nmt,
              const float* __restrict__ ea, const float* __restrict__ We,
              const int* __restrict__ order, const int* __restrict__ osrc,
              const int* __restrict__ rowstart,
              float* __restrict__ aggbb, float* __restrict__ pnum,
              float* __restrict__ pabc) {
  int t = threadIdx.x, d = t & 127, q = t >> 7;
  int g = blockIdx.x >> 3, e8 = blockIdx.x & 7;
  int nbase = g*256 + e8*32;
  float w[16];
  #pragma unroll
  for (int j = 0; j < 16; ++j) w[j] = We[j*128 + d];
  float aH[8] = {0,0,0,0,0,0,0,0};
  float aX[8] = {0,0,0,0,0,0,0,0};
  float aE[8] = {0,0,0,0,0,0,0,0};
  for (int nn = q; nn < 32; nn += 2) {
    int n = nbase + nn;
    unsigned int vn = xh[(size_t)n*128 + d];
    float xn = upk_x(vn), hn = upk_h(vn);
    const float4* pp = reinterpret_cast<const float4*>(nmt + (size_t)n*8);
    float4 p0 = pp[0], p1 = pp[1];
    float pc[8] = {p0.x,p0.y,p0.z,p0.w,p1.x,p1.y,p1.z,p1.w};
    float bsq[8];
    #pragma unroll
    for (int rc = 0; rc < 8; ++rc) {
      aH[rc] += pc[rc]*hn; aX[rc] += pc[rc]*xn;
      bsq[rc] = pc[rc]*pc[rc];
    }
    int ln = n - g*256;
    int start = rowstart[n];
    int end = (ln == 255) ? 1024 : rowstart[n+1];
    float agga = 0.f;
    for (int jj = start; jj < end; ++jj) {
      int e  = order[g*1024 + jj];
      int sg = osrc[g*1024 + jj];
      const float4* er = reinterpret_cast<const float4*>(ea + ((size_t)g*1024 + e)*16);
      float4 a0 = er[0], a1 = er[1], a2 = er[2], a3 = er[3];
      float ev = a0.x*w[0] + a0.y*w[1] + a0.z*w[2] + a0.w*w[3]
               + a1.x*w[4] + a1.y*w[5] + a1.z*w[6] + a1.w*w[7]
               + a2.x*w[8] + a2.y*w[9] + a2.z*w[10]+ a2.w*w[11]
               + a3.x*w[12]+ a3.y*w[13]+ a3.z*w[14]+ a3.w*w[15];
      unsigned int vs = xh[(size_t)sg*128 + d];
      agga += upk_x(vs) + ev;
      float hv = upk_h(vs) + ev;
      const float4* qq = reinterpret_cast<const float4*>(nmt + (size_t)sg*8);
      float4 q0 = qq[0], q1 = qq[1];
      float qc[8] = {q0.x,q0.y,q0.z,q0.w,q1.x,q1.y,q1.z,q1.w};
      #pragma unroll
      for (int rc = 0; rc < 8; ++rc) aE[rc] += bsq[rc]*qc[rc]*hv;
    }
    aggbb[(size_t)n*128 + d] = agga;
  }
  int slot = e8*2 + q;
  #pragma unroll
  for (int rc = 0; rc < 8; ++rc) {
    pnum[(((size_t)rc*Gg + g)*16 + slot)*128 + d] = aH[rc] + aE[rc];
    pabc[(((size_t)rc*Gg + g)*16 + slot)*128 + d] = aX[rc];
  }
}

// K4: centroid-pair weights Wcc per (r,g) + global max
__global__ __launch_bounds__(256)
void k_wcc(const float* __restrict__ nmt, const int* __restrict__ ei,
           float* __restrict__ wcc, unsigned int* __restrict__ maxbits) {
  __shared__ float red[20];
  int t = threadIdx.x, g = blockIdx.x;
  if (t < 20) red[t] = 0.f;
  __syncthreads();
  float w[20];
  #pragma unroll
  for (int i = 0; i < 20; ++i) w[i] = 0.f;
  #pragma unroll
  for (int j = 0; j < 4; ++j) {
    int e = g*1024 + t + j*256;
    int s = ei[e], dd = ei[Ee + e];
    const float4* ps4 = reinterpret_cast<const float4*>(nmt + (size_t)s*8);
    const float4* pt4 = reinterpret_cast<const float4*>(nmt + (size_t)dd*8);
    float4 s0 = ps4[0], s1 = ps4[1], t0 = pt4[0], t1 = pt4[1];
    float ps[8] = {s0.x,s0.y,s0.z,s0.w,s1.x,s1.y,s1.z,s1.w};
    float pt[8] = {t0.x,t0.y,t0.z,t0.w,t1.x,t1.y,t1.z,t1.w};
    #pragma unroll
    for (int r = 0; r < 2; ++r) {
      int b = r*4;
      w[r*10+0] += ps[b+0]*pt[b+1]; w[r*10+1] += ps[b+0]*pt[b+2]; w[r*10+2] += ps[b+0]*pt[b+3];
      w[r*10+3] += ps[b+1]*pt[b+2]; w[r*10+4] += ps[b+1]*pt[b+3]; w[r*10+5] += ps[b+2]*pt[b+3];
      w[r*10+6] += ps[b+0]*pt[b+0]; w[r*10+7] += ps[b+1]*pt[b+1];
      w[r*10+8] += ps[b+2]*pt[b+2]; w[r*10+9] += ps[b+3]*pt[b+3];
    }
  }
  #pragma unroll
  for (int i = 0; i < 20; ++i) {
    for (int off = 32; off > 0; off >>= 1) w[i] += __shfl_down(w[i], off);
  }
  if ((t & 63) == 0) {
    #pragma unroll
    for (int i = 0; i < 20; ++i) atomicAdd(&red[i], w[i]);
  }
  __syncthreads();
  if (t < 32) {
    int r = t >> 4, ij = t & 15, i = ij >> 2, j = ij & 3;
    float v;
    if (i == j) v = 0.5f * red[r*10 + 6 + i];
    else { int a = i < j ? i : j, b = i < j ? j : i;
           int p = (a == 0) ? (b - 1) : (a == 1) ? (b + 1) : 5;
           v = red[r*10 + p]; }
    wcc[(r*Gg + g)*16 + ij] = v;
    atomicMax(maxbits, __float_as_uint(v));
  }
}

// K5: cent_x = num/(den+1e-6); h_cent = relu(abc@Wbc + (Wcc_n@cent)@Wcc + cent@Wsc)
// num/abc summed from 16 partials here.
__global__ __launch_bounds__(128)
void k_hcent(const float* __restrict__ pnum, const float* __restrict__ den,
             const float* __restrict__ pabc, const float* __restrict__ wcc,
             const unsigned int* __restrict__ maxbits,
             const float* __restrict__ Wbc, const float* __restrict__ Wcc_,
             const float* __restrict__ Wsc2, float* __restrict__ hcent) {
  __shared__ float scent[512], sbc[512], sccs[512], swcc[16];
  int tid = threadIdx.x, r = blockIdx.x >> 7, g = blockIdx.x & 127;
  float inv = 1.f / (__uint_as_float(*maxbits) + 1e-9f);
  if (tid < 16) swcc[tid] = wcc[(r*Gg + g)*16 + tid] * inv;
  for (int c = 0; c < 4; ++c) {
    int rc = r*4 + c;
    float nv = 0.f, av = 0.f;
    #pragma unroll
    for (int s = 0; s < 16; ++s) {
      nv += pnum[(((size_t)rc*Gg + g)*16 + s)*128 + tid];
      av += pabc[(((size_t)rc*Gg + g)*16 + s)*128 + tid];
    }
    float dn = den[rc*Gg + g] + 1e-6f;
    scent[c*128 + tid] = nv / dn;
    sbc[c*128 + tid]   = av;
  }
  __syncthreads();
  for (int i = 0; i < 4; ++i) {
    sccs[i*128 + tid] = swcc[i*4+0]*scent[tid]       + swcc[i*4+1]*scent[128 + tid]
                      + swcc[i*4+2]*scent[256 + tid] + swcc[i*4+3]*scent[384 + tid];
  }
  __syncthreads();
  for (int c = 0; c < 4; ++c) {
    float acc = 0.f;
    for (int k = 0; k < 128; ++k) {
      acc += sbc[c*128 + k]   * Wbc[k*128 + tid];
      acc += sccs[c*128 + k]  * Wcc_[k*128 + tid];
      acc += scent[c*128 + k] * Wsc2[k*128 + tid];
    }
    hcent[((r*Gg + g)*4 + c)*128 + tid] = fmaxf(acc, 0.f);
  }
}

// K6: merged bbsb+hbase: bbsb = aggbb@Wbb + x@Wsb (regs);
// per r: agg_cb = sum_c nm*h_cent; h_base = relu(bbsb + agg_cb@Wcb);
// mean over r; per-graph col sums -> gsum (LDS-reduced, 128 atomics/block).
__global__ __launch_bounds__(256)
void k_hbase(const float* __restrict__ aggbb, const unsigned int* __restrict__ xh,
             const float* __restrict__ nmt, const float* __restrict__ hcent,
             const float* __restrict__ Wbb, const float* __restrict__ Wsb,
             const float* __restrict__ Wcb, float* __restrict__ gsum) {
  __shared__ float sa[32*128];          // 16 KB; aliased as scb in r-loop
  __shared__ unsigned int sxh[32*128];  // 16 KB
  __shared__ float shc[512];
  __shared__ float pred[8*128];
  float* scb = sa;
  int tid = threadIdx.x, n0 = blockIdx.x*32, g = n0 >> 8;
  int ct = tid & 31, rt = tid >> 5;
  int c0 = ct*4, r0 = rt*4;
  for (int j = tid; j < 4096; j += 256) {
    sa[j]  = aggbb[(size_t)n0*128 + j];
    sxh[j] = xh[(size_t)n0*128 + j];
  }
  __syncthreads();
  float bb[4][4];
  #pragma unroll
  for (int i = 0; i < 4; ++i)
    #pragma unroll
    for (int j = 0; j < 4; ++j) bb[i][j] = 0.f;
  for (int k = 0; k < 128; ++k) {
    float4 w1 = *reinterpret_cast<const float4*>(&Wbb[k*128 + c0]);
    float4 w2 = *reinterpret_cast<const float4*>(&Wsb[k*128 + c0]);
    #pragma unroll
    for (int i = 0; i < 4; ++i) {
      float a1 = sa[(r0+i)*128 + k];
      float a2 = upk_x(sxh[(r0+i)*128 + k]);
      bb[i][0] += a1*w1.x + a2*w2.x; bb[i][1] += a1*w1.y + a2*w2.y;
      bb[i][2] += a1*w1.z + a2*w2.z; bb[i][3] += a1*w1.w + a2*w2.w;
    }
  }
  __syncthreads();   // all done reading sa -> safe to alias scb
  float msum[4][4];
  #pragma unroll
  for (int i = 0; i < 4; ++i)
    #pragma unroll
    for (int j = 0; j < 4; ++j) msum[i][j] = 0.f;
  for (int r = 0; r < 2; ++r) {
    for (int j = tid; j < 512; j += 256) shc[j] = hcent[((size_t)(r*Gg + g)*4)*128 + j];
    __syncthreads();  // shc ready; also guards prior-iter scb reads
    for (int j = tid; j < 4096; j += 256) {
      int node = j >> 7, k = j & 127;
      size_t nb = (size_t)(n0 + node)*8 + r*4;
      scb[j] = nmt[nb+0]*shc[k]       + nmt[nb+1]*shc[128 + k]
             + nmt[nb+2]*shc[256 + k] + nmt[nb+3]*shc[384 + k];
    }
    __syncthreads();
    float acc[4][4];
    #pragma unroll
    for (int i = 0; i < 4; ++i)
      #pragma unroll
      for (int j = 0; j < 4; ++j) acc[i][j] = 0.f;
    for (int k = 0; k < 128; ++k) {
      float4 wv = *reinterpret_cast<const float4*>(&Wcb[k*128 + c0]);
      #pragma unroll
      for (int i = 0; i < 4; ++i) {
        float a = scb[(r0+i)*128 + k];
        acc[i][0] += a*wv.x; acc[i][1] += a*wv.y; acc[i][2] += a*wv.z; acc[i][3] += a*wv.w;
      }
    }
    #pragma unroll
    for (int i = 0; i < 4; ++i)
      #pragma unroll
      for (int j = 0; j < 4; ++j)
        msum[i][j] += 0.5f * fmaxf(bb[i][j] + acc[i][j], 0.f);
    __syncthreads();  // done reading scb before next r overwrites
  }
  // column partial sums -> gsum
  #pragma unroll
  for (int j = 0; j < 4; ++j) {
    float s = msum[0][j] + msum[1][j] + msum[2][j] + msum[3][j];
    pred[rt*128 + c0 + j] = s;
  }
  __syncthreads();
  if (rt == 0) {
    #pragma unroll
    for (int j = 0; j < 4; ++j) {
      float s = 0.f;
      #pragma unroll
      for (int k = 0; k < 8; ++k) s += pred[k*128 + c0 + j];
      atomicAdd(&gsum[g*128 + c0 + j], s);
    }
  }
}

// K7: graph mean + W_inter + W_out head
__global__ __launch_bounds__(128)
void k_out(const float* __restrict__ gsum, const float* __restrict__ Wint,
           const float* __restrict__ bint, const float* __restrict__ Wout,
           const float* __restrict__ bout, float* __restrict__ out) {
  __shared__ float ss[128], sge[128];
  int tid = threadIdx.x, g = blockIdx.x;
  ss[tid] = gsum[g*128 + tid] * (1.f/256.f);
  __syncthreads();
  float ge = bint[tid];
  for (int k = 0; k < 128; ++k) ge += ss[k] * Wint[k*128 + tid];
  sge[tid] = ge;
  __syncthreads();
  if (tid < 10) {
    float o = bout[tid];
    for (int d = 0; d < 128; ++d) o += sge[d] * Wout[d*10 + tid];
    out[g*10 + tid] = o;
  }
}

extern "C" void kernel_launch(void* const* d_in, const int* in_sizes, int n_in,
                              void* d_out, int out_size, void* d_ws, size_t ws_size,
                              hipStream_t stream) {
  const float* xf   = (const float*)d_in[0];
  const float* ea   = (const float*)d_in[1];
  const float* Wa   = (const float*)d_in[2];
  const float* ba   = (const float*)d_in[3];
  const float* Wsc  = (const float*)d_in[4];
  const float* We   = (const float*)d_in[5];
  const float* Wb2c = (const float*)d_in[6];
  const float* Wbb  = (const float*)d_in[7];
  const float* Wbc  = (const float*)d_in[8];
  const float* Wcb  = (const float*)d_in[9];
  const float* WccW = (const float*)d_in[10];
  const float* Wsb  = (const float*)d_in[11];
  const float* Wsc2 = (const float*)d_in[12];
  const float* Wint = (const float*)d_in[13];
  const float* bint = (const float*)d_in[14];
  const float* Wout = (const float*)d_in[15];
  const float* bout = (const float*)d_in[16];
  const int*   ei   = (const int*)d_in[17];

  // Workspace layout (float offsets); total 13,292,608 f = 53.2 MB
  float* ws    = (float*)d_ws;
  unsigned int* xh = (unsigned int*)ws;              // [N,128] packed   (4,194,304)
  float* nmt   = ws + 4194304;                       // [N,8]            (262,144)
  float* hcent = ws + 4456448;                       // [R,G,4,128]      (131,072)
  float* wcc   = ws + 4587520;                       // [R,G,16]         (4,096)
  float* aggbb = ws + 4591616;                       // [N,128]          (4,194,304)
  int*   order = (int*)(ws + 8785920);               // [E]              (131,072)
  int*   osrc  = (int*)(ws + 8916992);               // [E]              (131,072)
  int*   rowst = (int*)(ws + 9048064);               // [N]              (32,768)
  float* pnum  = ws + 9080832;                       // [8,G,16,128]     (2,097,152)
  float* pabc  = ws + 11177984;                      // [8,G,16,128]     (2,097,152)
  float* den   = ws + 13275136;                      // [8,G]            (1,024)
  float* gsum  = ws + 13276160;                      // [G,128]          (16,384)
  unsigned int* maxbits = (unsigned int*)(ws + 13292544); // (64)

  hipMemsetAsync(gsum, 0, (16384 + 64) * sizeof(float), stream);

  k_atom  <<<Nn/32, 256, 0, stream>>>(xf, Wa, ba, Wsc, Wb2c, xh, nmt);
  k_csr   <<<Gg,    256, 0, stream>>>(ei, nmt, order, osrc, rowst, den);
  k_gather<<<Gg*8,  256, 0, stream>>>(xh, nmt, ea, We, order, osrc, rowst,
                                      aggbb, pnum, pabc);
  k_wcc   <<<Gg,    256, 0, stream>>>(nmt, ei, wcc, maxbits);
  k_hcent <<<2*Gg,  128, 0, stream>>>(pnum, den, pabc, wcc, maxbits, Wbc, WccW, Wsc2, hcent);
  k_hbase <<<Nn/32, 256, 0, stream>>>(aggbb, xh, nmt, hcent, Wbb, Wsb, Wcb, gsum);
  k_out   <<<Gg,    128, 0, stream>>>(gsum, Wint, bint, Wout, bout, (float*)d_out);
}

// Round 7
// 307.347 us; speedup vs baseline: 1.8195x; 1.0876x over previous
//
#include <hip/hip_runtime.h>
#include <hip/hip_bf16.h>

// Problem sizes (fixed)
#define Nn 32768   // nodes
#define Ee 131072  // edges
#define Gg 128     // graphs
#define Dd 128

using bf16 = __hip_bfloat16;
typedef __attribute__((ext_vector_type(8))) short bf16x8;
typedef __attribute__((ext_vector_type(4))) float f32x4;

__device__ __forceinline__ float b2f(bf16 v){ return __bfloat162float(v); }
__device__ __forceinline__ bf16  f2b(float v){ return __float2bfloat16(v); }
__device__ __forceinline__ unsigned short bf16bits(float v){
  union { bf16 b; unsigned short u; } cv; cv.b = f2b(v); return cv.u;
}
__device__ __forceinline__ unsigned int packxh(float xv, float hv){
  return ((unsigned int)bf16bits(hv) << 16) | (unsigned int)bf16bits(xv);
}
__device__ __forceinline__ float upk_x(unsigned int v){ return __uint_as_float(v << 16); }
__device__ __forceinline__ float upk_h(unsigned int v){ return __uint_as_float(v & 0xffff0000u); }

// K0: repack Wbb/Wsb/Wcb fp32 [k][n] -> bf16 transposed [n][k]
__global__ __launch_bounds__(128)
void k_wrep(const float* __restrict__ Wbb, const float* __restrict__ Wsb,
            const float* __restrict__ Wcb, unsigned short* __restrict__ Wbbp,
            unsigned short* __restrict__ Wsbp, unsigned short* __restrict__ Wcbp) {
  int mat = blockIdx.x >> 7, n = blockIdx.x & 127, k = threadIdx.x;
  const float* src = (mat == 0) ? Wbb : (mat == 1) ? Wsb : Wcb;
  unsigned short* dst = (mat == 0) ? Wbbp : (mat == 1) ? Wsbp : Wcbp;
  dst[n*128 + k] = bf16bits(src[k*128 + n]);
}

// K1: x = xf@Wa + ba; nmt[n][rc] = softmax_c(x@Wsc); h = relu(x@Wb2c).
// Register-tiled 4x4; x,h packed bf16x2 into xh[N,128].
__global__ __launch_bounds__(256)
void k_atom(const float* __restrict__ xf, const float* __restrict__ Wa,
            const float* __restrict__ ba, const float* __restrict__ Wsc,
            const float* __restrict__ Wb2c,
            unsigned int* __restrict__ xh, float* __restrict__ nmt) {
  __shared__ float sxf[32*64];
  __shared__ float sx[32*128];
  __shared__ float ss[32*8];
  int tid = threadIdx.x, n0 = blockIdx.x * 32;
  int ct = tid & 31, rt = tid >> 5;
  int c0 = ct*4, r0 = rt*4;
  for (int j = tid; j < 2048; j += 256) sxf[j] = xf[n0*64 + j];
  __syncthreads();
  float acc[4][4];
  #pragma unroll
  for (int i = 0; i < 4; ++i)
    #pragma unroll
    for (int j = 0; j < 4; ++j) acc[i][j] = ba[c0+j];
  for (int k = 0; k < 64; ++k) {
    float4 bv = *reinterpret_cast<const float4*>(&Wa[k*128 + c0]);
    #pragma unroll
    for (int i = 0; i < 4; ++i) {
      float a = sxf[(r0+i)*64 + k];
      acc[i][0] += a*bv.x; acc[i][1] += a*bv.y; acc[i][2] += a*bv.z; acc[i][3] += a*bv.w;
    }
  }
  #pragma unroll
  for (int i = 0; i < 4; ++i)
    #pragma unroll
    for (int j = 0; j < 4; ++j) sx[(r0+i)*128 + c0+j] = acc[i][j];
  __syncthreads();
  {
    int node = tid >> 3, col = tid & 7;
    float s = 0.f;
    for (int d = 0; d < 128; ++d) s += sx[node*128 + d] * Wsc[d*8 + col];
    ss[node*8 + col] = s;
  }
  __syncthreads();
  if (tid < 64) {
    int node = tid >> 1, k = tid & 1;
    float v0 = ss[node*8 + 0 + k], v1 = ss[node*8 + 2 + k];
    float v2 = ss[node*8 + 4 + k], v3 = ss[node*8 + 6 + k];
    float mx = fmaxf(fmaxf(v0, v1), fmaxf(v2, v3));
    float e0 = expf(v0-mx), e1 = expf(v1-mx), e2 = expf(v2-mx), e3 = expf(v3-mx);
    float inv = 1.f / (e0+e1+e2+e3);
    size_t nb = (size_t)(n0 + node)*8 + k*4;
    nmt[nb+0] = e0*inv; nmt[nb+1] = e1*inv; nmt[nb+2] = e2*inv; nmt[nb+3] = e3*inv;
  }
  float acc2[4][4];
  #pragma unroll
  for (int i = 0; i < 4; ++i)
    #pragma unroll
    for (int j = 0; j < 4; ++j) acc2[i][j] = 0.f;
  for (int k = 0; k < 128; ++k) {
    float4 bv = *reinterpret_cast<const float4*>(&Wb2c[k*128 + c0]);
    #pragma unroll
    for (int i = 0; i < 4; ++i) {
      float a = sx[(r0+i)*128 + k];
      acc2[i][0] += a*bv.x; acc2[i][1] += a*bv.y; acc2[i][2] += a*bv.z; acc2[i][3] += a*bv.w;
    }
  }
  #pragma unroll
  for (int i = 0; i < 4; ++i)
    #pragma unroll
    for (int j = 0; j < 4; ++j)
      xh[(size_t)(n0+r0+i)*128 + c0+j] = packxh(acc[i][j], fmaxf(acc2[i][j], 0.f));
}

// K2: per-graph dst-CSR build (+ den = per-graph sum of nmt)
__global__ __launch_bounds__(256)
void k_csr(const int* __restrict__ ei, const float* __restrict__ nmt,
           int* __restrict__ order, int* __restrict__ osrc,
           int* __restrict__ rowstart, float* __restrict__ den) {
  __shared__ int cnt[256], off[256], sdl[1024];
  __shared__ float sden[256*8];
  int t = threadIdx.x, g = blockIdx.x;
  cnt[t] = 0;
  __syncthreads();
  #pragma unroll
  for (int j = 0; j < 4; ++j) {
    int e = t + j*256;
    int dl = ei[Ee + g*1024 + e] - g*256;
    sdl[e] = dl;
    atomicAdd(&cnt[dl], 1);
  }
  {
    const float4* p = reinterpret_cast<const float4*>(nmt + (size_t)(g*256 + t)*8);
    float4 a = p[0], b = p[1];
    sden[t*8+0]=a.x; sden[t*8+1]=a.y; sden[t*8+2]=a.z; sden[t*8+3]=a.w;
    sden[t*8+4]=b.x; sden[t*8+5]=b.y; sden[t*8+6]=b.z; sden[t*8+7]=b.w;
  }
  __syncthreads();
  off[t] = cnt[t];
  __syncthreads();
  for (int s = 1; s < 256; s <<= 1) {
    int v = (t >= s) ? off[t - s] : 0;
    __syncthreads();
    off[t] += v;
    __syncthreads();
  }
  int startv = off[t] - cnt[t];
  rowstart[g*256 + t] = startv;
  off[t] = startv;
  __syncthreads();
  #pragma unroll
  for (int j = 0; j < 4; ++j) {
    int e = t + j*256;
    int pos = atomicAdd(&off[sdl[e]], 1);
    order[g*1024 + pos] = e;
    osrc[g*1024 + pos]  = ei[g*1024 + e];
  }
  if (t < 8) {
    float s = 0.f;
    for (int p = 0; p < 256; ++p) s += sden[p*8 + t];
    den[t*Gg + g] = s;
  }
}

// K3: dst-CSR gather. grid (g, 16th)=2048 blocks; thread (q,d).
//   aggbb16[n,:] = bf16( sum_{e in(n)} x[src]+eev )
//   pnum/pabc partials per (rc, g, slot16)  (q-halves combined in LDS)
__global__ __launch_bounds__(256)
void k_gather(const unsigned int* __restrict__ xh, const float* __restrict__ nmt,
              const float* __restrict__ ea, const float* __restrict__ We,
              const int* __restrict__ order, const int* __restrict__ osrc,
              const int* __restrict__ rowstart,
              unsigned short* __restrict__ aggbb16, float* __restrict__ pnum,
              float* __restrict__ pabc) {
  __shared__ float combN[8*128], combA[8*128];
  int t = threadIdx.x, d = t & 127, q = t >> 7;
  int g = blockIdx.x >> 4, e16 = blockIdx.x & 15;
  int nbase = g*256 + e16*16;
  float w[16];
  #pragma unroll
  for (int j = 0; j < 16; ++j) w[j] = We[j*128 + d];
  float aH[8] = {0,0,0,0,0,0,0,0};
  float aX[8] = {0,0,0,0,0,0,0,0};
  float aE[8] = {0,0,0,0,0,0,0,0};
  for (int nn = q; nn < 16; nn += 2) {
    int n = nbase + nn;
    unsigned int vn = xh[(size_t)n*128 + d];
    float xn = upk_x(vn), hn = upk_h(vn);
    const float4* pp = reinterpret_cast<const float4*>(nmt + (size_t)n*8);
    float4 p0 = pp[0], p1 = pp[1];
    float pc[8] = {p0.x,p0.y,p0.z,p0.w,p1.x,p1.y,p1.z,p1.w};
    float bsq[8];
    #pragma unroll
    for (int rc = 0; rc < 8; ++rc) {
      aH[rc] += pc[rc]*hn; aX[rc] += pc[rc]*xn;
      bsq[rc] = pc[rc]*pc[rc];
    }
    int ln = n - g*256;
    int start = rowstart[n];
    int end = (ln == 255) ? 1024 : rowstart[n+1];
    float agga = 0.f;
    for (int jj = start; jj < end; ++jj) {
      int e  = order[g*1024 + jj];
      int sg = osrc[g*1024 + jj];
      const float4* er = reinterpret_cast<const float4*>(ea + ((size_t)g*1024 + e)*16);
      float4 a0 = er[0], a1 = er[1], a2 = er[2], a3 = er[3];
      float ev = a0.x*w[0] + a0.y*w[1] + a0.z*w[2] + a0.w*w[3]
               + a1.x*w[4] + a1.y*w[5] + a1.z*w[6] + a1.w*w[7]
               + a2.x*w[8] + a2.y*w[9] + a2.z*w[10]+ a2.w*w[11]
               + a3.x*w[12]+ a3.y*w[13]+ a3.z*w[14]+ a3.w*w[15];
      unsigned int vs = xh[(size_t)sg*128 + d];
      agga += upk_x(vs) + ev;
      float hv = upk_h(vs) + ev;
      const float4* qq = reinterpret_cast<const float4*>(nmt + (size_t)sg*8);
      float4 q0 = qq[0], q1 = qq[1];
      float qc[8] = {q0.x,q0.y,q0.z,q0.w,q1.x,q1.y,q1.z,q1.w};
      #pragma unroll
      for (int rc = 0; rc < 8; ++rc) aE[rc] += bsq[rc]*qc[rc]*hv;
    }
    aggbb16[(size_t)n*128 + d] = bf16bits(agga);
  }
  if (q == 1) {
    #pragma unroll
    for (int rc = 0; rc < 8; ++rc) { combN[rc*128+d] = aH[rc]+aE[rc]; combA[rc*128+d] = aX[rc]; }
  }
  __syncthreads();
  if (q == 0) {
    #pragma unroll
    for (int rc = 0; rc < 8; ++rc) {
      pnum[(((size_t)rc*Gg + g)*16 + e16)*128 + d] = aH[rc] + aE[rc] + combN[rc*128+d];
      pabc[(((size_t)rc*Gg + g)*16 + e16)*128 + d] = aX[rc] + combA[rc*128+d];
    }
  }
}

// K4: centroid-pair weights Wcc per (r,g) + global max
__global__ __launch_bounds__(256)
void k_wcc(const float* __restrict__ nmt, const int* __restrict__ ei,
           float* __restrict__ wcc, unsigned int* __restrict__ maxbits) {
  __shared__ float red[20];
  int t = threadIdx.x, g = blockIdx.x;
  if (t < 20) red[t] = 0.f;
  __syncthreads();
  float w[20];
  #pragma unroll
  for (int i = 0; i < 20; ++i) w[i] = 0.f;
  #pragma unroll
  for (int j = 0; j < 4; ++j) {
    int e = g*1024 + t + j*256;
    int s = ei[e], dd = ei[Ee + e];
    const float4* ps4 = reinterpret_cast<const float4*>(nmt + (size_t)s*8);
    const float4* pt4 = reinterpret_cast<const float4*>(nmt + (size_t)dd*8);
    float4 s0 = ps4[0], s1 = ps4[1], t0 = pt4[0], t1 = pt4[1];
    float ps[8] = {s0.x,s0.y,s0.z,s0.w,s1.x,s1.y,s1.z,s1.w};
    float pt[8] = {t0.x,t0.y,t0.z,t0.w,t1.x,t1.y,t1.z,t1.w};
    #pragma unroll
    for (int r = 0; r < 2; ++r) {
      int b = r*4;
      w[r*10+0] += ps[b+0]*pt[b+1]; w[r*10+1] += ps[b+0]*pt[b+2]; w[r*10+2] += ps[b+0]*pt[b+3];
      w[r*10+3] += ps[b+1]*pt[b+2]; w[r*10+4] += ps[b+1]*pt[b+3]; w[r*10+5] += ps[b+2]*pt[b+3];
      w[r*10+6] += ps[b+0]*pt[b+0]; w[r*10+7] += ps[b+1]*pt[b+1];
      w[r*10+8] += ps[b+2]*pt[b+2]; w[r*10+9] += ps[b+3]*pt[b+3];
    }
  }
  #pragma unroll
  for (int i = 0; i < 20; ++i) {
    for (int off = 32; off > 0; off >>= 1) w[i] += __shfl_down(w[i], off);
  }
  if ((t & 63) == 0) {
    #pragma unroll
    for (int i = 0; i < 20; ++i) atomicAdd(&red[i], w[i]);
  }
  __syncthreads();
  if (t < 32) {
    int r = t >> 4, ij = t & 15, i = ij >> 2, j = ij & 3;
    float v;
    if (i == j) v = 0.5f * red[r*10 + 6 + i];
    else { int a = i < j ? i : j, b = i < j ? j : i;
           int p = (a == 0) ? (b - 1) : (a == 1) ? (b + 1) : 5;
           v = red[r*10 + p]; }
    wcc[(r*Gg + g)*16 + ij] = v;
    atomicMax(maxbits, __float_as_uint(v));
  }
}

// K5: cent_x = num/(den+1e-6); h_cent = relu(abc@Wbc + (Wcc_n@cent)@Wcc + cent@Wsc)
__global__ __launch_bounds__(128)
void k_hcent(const float* __restrict__ pnum, const float* __restrict__ den,
             const float* __restrict__ pabc, const float* __restrict__ wcc,
             const unsigned int* __restrict__ maxbits,
             const float* __restrict__ Wbc, const float* __restrict__ Wcc_,
             const float* __restrict__ Wsc2, float* __restrict__ hcent) {
  __shared__ float scent[512], sbc[512], sccs[512], swcc[16];
  int tid = threadIdx.x, r = blockIdx.x >> 7, g = blockIdx.x & 127;
  float inv = 1.f / (__uint_as_float(*maxbits) + 1e-9f);
  if (tid < 16) swcc[tid] = wcc[(r*Gg + g)*16 + tid] * inv;
  for (int c = 0; c < 4; ++c) {
    int rc = r*4 + c;
    float nv = 0.f, av = 0.f;
    #pragma unroll
    for (int s = 0; s < 16; ++s) {
      nv += pnum[(((size_t)rc*Gg + g)*16 + s)*128 + tid];
      av += pabc[(((size_t)rc*Gg + g)*16 + s)*128 + tid];
    }
    float dn = den[rc*Gg + g] + 1e-6f;
    scent[c*128 + tid] = nv / dn;
    sbc[c*128 + tid]   = av;
  }
  __syncthreads();
  for (int i = 0; i < 4; ++i) {
    sccs[i*128 + tid] = swcc[i*4+0]*scent[tid]       + swcc[i*4+1]*scent[128 + tid]
                      + swcc[i*4+2]*scent[256 + tid] + swcc[i*4+3]*scent[384 + tid];
  }
  __syncthreads();
  for (int c = 0; c < 4; ++c) {
    float acc = 0.f;
    for (int k = 0; k < 128; ++k) {
      acc += sbc[c*128 + k]   * Wbc[k*128 + tid];
      acc += sccs[c*128 + k]  * Wcc_[k*128 + tid];
      acc += scent[c*128 + k] * Wsc2[k*128 + tid];
    }
    hcent[((r*Gg + g)*4 + c)*128 + tid] = fmaxf(acc, 0.f);
  }
}

// K6 (MFMA): bbsb = aggbb@Wbb + x@Wsb; per r: scb = (nm x hcent);
// h_base = relu(bbsb + scb@Wcb); mean over r; column sums -> gsum.
// 64 nodes/block, 4 waves; MFMA 16x16x32 bf16. A tiles in padded LDS [64][136].
__global__ __launch_bounds__(256)
void k_hbase(const unsigned short* __restrict__ aggbb16,
             const unsigned int* __restrict__ xh,
             const float* __restrict__ nmt, const float* __restrict__ hcent,
             const unsigned short* __restrict__ Wbbp,
             const unsigned short* __restrict__ Wsbp,
             const unsigned short* __restrict__ Wcbp,
             float* __restrict__ gsum) {
  __shared__ unsigned short A1[64*136];   // aggbb tile (17408 B)
  __shared__ unsigned short A2[64*136];   // x tile; aliased as SB (scb) later
  __shared__ float shc[512];
  __shared__ float snm[256];              // 64 nodes x 4 centroids (this r)
  __shared__ float pred[128];
  int tid = threadIdx.x, n0 = blockIdx.x*64, g = n0 >> 8;
  int lane = tid & 63, wv = tid >> 6;
  int m = lane & 15, quad = lane >> 4;
  int rbase = wv*16;
  // stage A1 (bf16 aggbb rows)
  for (int j = tid; j < 1024; j += 256) {
    int row = j >> 4, col = (j & 15) * 8;
    uint4 v = *reinterpret_cast<const uint4*>(aggbb16 + (size_t)(n0+row)*128 + col);
    *reinterpret_cast<uint4*>(&A1[row*136 + col]) = v;
  }
  // stage A2 (x bf16 from packed xh low halves)
  for (int j = tid; j < 2048; j += 256) {
    int row = j >> 5, col = (j & 31) * 4;
    uint4 v = *reinterpret_cast<const uint4*>(xh + (size_t)(n0+row)*128 + col);
    uint2 o;
    o.x = (v.x & 0xffffu) | (v.y << 16);
    o.y = (v.z & 0xffffu) | (v.w << 16);
    *reinterpret_cast<uint2*>(&A2[row*136 + col]) = o;
  }
  __syncthreads();
  // GEMM1: bb = A1@Wbbp' + A2@Wsbp'  (C-frags, 8 n-tiles)
  f32x4 bb[8];
  #pragma unroll
  for (int nt = 0; nt < 8; ++nt) bb[nt] = (f32x4){0.f,0.f,0.f,0.f};
  const short* a1r = (const short*)&A1[(rbase + m)*136];
  const short* a2r = (const short*)&A2[(rbase + m)*136];
  #pragma unroll
  for (int nt = 0; nt < 8; ++nt) {
    #pragma unroll
    for (int kk = 0; kk < 4; ++kk) {
      int ko = kk*32 + quad*8;
      bf16x8 av1 = *reinterpret_cast<const bf16x8*>(a1r + ko);
      bf16x8 wv1 = *reinterpret_cast<const bf16x8*>((const short*)Wbbp + (nt*16 + m)*128 + ko);
      bb[nt] = __builtin_amdgcn_mfma_f32_16x16x32_bf16(av1, wv1, bb[nt], 0, 0, 0);
      bf16x8 av2 = *reinterpret_cast<const bf16x8*>(a2r + ko);
      bf16x8 wv2 = *reinterpret_cast<const bf16x8*>((const short*)Wsbp + (nt*16 + m)*128 + ko);
      bb[nt] = __builtin_amdgcn_mfma_f32_16x16x32_bf16(av2, wv2, bb[nt], 0, 0, 0);
    }
  }
  __syncthreads();   // all waves done with A2 -> safe to reuse as SB
  unsigned short* SB = A2;
  f32x4 msum[8];
  #pragma unroll
  for (int nt = 0; nt < 8; ++nt) msum[nt] = (f32x4){0.f,0.f,0.f,0.f};
  for (int r = 0; r < 2; ++r) {
    for (int j = tid; j < 512; j += 256) shc[j] = hcent[((size_t)(r*Gg + g)*4)*128 + j];
    if (tid < 256) snm[tid] = nmt[(size_t)(n0 + (tid >> 2))*8 + r*4 + (tid & 3)];
    __syncthreads();  // staging visible; prev-iter GEMM2 done (loop-end sync)
    for (int j = tid; j < 8192; j += 256) {
      int node = j >> 7, k = j & 127;
      float v = snm[node*4+0]*shc[k]       + snm[node*4+1]*shc[128 + k]
              + snm[node*4+2]*shc[256 + k] + snm[node*4+3]*shc[384 + k];
      SB[node*136 + k] = bf16bits(v);
    }
    __syncthreads();
    f32x4 aw[8];
    #pragma unroll
    for (int nt = 0; nt < 8; ++nt) aw[nt] = (f32x4){0.f,0.f,0.f,0.f};
    const short* sbr = (const short*)&SB[(rbase + m)*136];
    #pragma unroll
    for (int nt = 0; nt < 8; ++nt) {
      #pragma unroll
      for (int kk = 0; kk < 4; ++kk) {
        int ko = kk*32 + quad*8;
        bf16x8 av = *reinterpret_cast<const bf16x8*>(sbr + ko);
        bf16x8 wvv = *reinterpret_cast<const bf16x8*>((const short*)Wcbp + (nt*16 + m)*128 + ko);
        aw[nt] = __builtin_amdgcn_mfma_f32_16x16x32_bf16(av, wvv, aw[nt], 0, 0, 0);
      }
    }
    #pragma unroll
    for (int nt = 0; nt < 8; ++nt) {
      #pragma unroll
      for (int i = 0; i < 4; ++i)
        msum[nt][i] += 0.5f * fmaxf(bb[nt][i] + aw[nt][i], 0.f);
    }
    __syncthreads();  // done reading SB/shc before next r restages
  }
  // column sums: lane holds rows quad*4+i of col nt*16+m
  if (tid < 128) pred[tid] = 0.f;
  __syncthreads();
  #pragma unroll
  for (int nt = 0; nt < 8; ++nt) {
    float s = msum[nt][0] + msum[nt][1] + msum[nt][2] + msum[nt][3];
    atomicAdd(&pred[nt*16 + m], s);
  }
  __syncthreads();
  if (tid < 128) atomicAdd(&gsum[g*128 + tid], pred[tid]);
}

// K7: graph mean + W_inter + W_out head
__global__ __launch_bounds__(128)
void k_out(const float* __restrict__ gsum, const float* __restrict__ Wint,
           const float* __restrict__ bint, const float* __restrict__ Wout,
           const float* __restrict__ bout, float* __restrict__ out) {
  __shared__ float ss[128], sge[128];
  int tid = threadIdx.x, g = blockIdx.x;
  ss[tid] = gsum[g*128 + tid] * (1.f/256.f);
  __syncthreads();
  float ge = bint[tid];
  for (int k = 0; k < 128; ++k) ge += ss[k] * Wint[k*128 + tid];
  sge[tid] = ge;
  __syncthreads();
  if (tid < 10) {
    float o = bout[tid];
    for (int d = 0; d < 128; ++d) o += sge[d] * Wout[d*10 + tid];
    out[g*10 + tid] = o;
  }
}

extern "C" void kernel_launch(void* const* d_in, const int* in_sizes, int n_in,
                              void* d_out, int out_size, void* d_ws, size_t ws_size,
                              hipStream_t stream) {
  const float* xf   = (const float*)d_in[0];
  const float* ea   = (const float*)d_in[1];
  const float* Wa   = (const float*)d_in[2];
  const float* ba   = (const float*)d_in[3];
  const float* Wsc  = (const float*)d_in[4];
  const float* We   = (const float*)d_in[5];
  const float* Wb2c = (const float*)d_in[6];
  const float* Wbb  = (const float*)d_in[7];
  const float* Wbc  = (const float*)d_in[8];
  const float* Wcb  = (const float*)d_in[9];
  const float* WccW = (const float*)d_in[10];
  const float* Wsb  = (const float*)d_in[11];
  const float* Wsc2 = (const float*)d_in[12];
  const float* Wint = (const float*)d_in[13];
  const float* bint = (const float*)d_in[14];
  const float* Wout = (const float*)d_in[15];
  const float* bout = (const float*)d_in[16];
  const int*   ei   = (const int*)d_in[17];

  // Workspace layout (float offsets); total ~11.23M f = 44.9 MB
  float* ws    = (float*)d_ws;
  unsigned int* xh = (unsigned int*)ws;                    // [N,128]      (4,194,304)
  float* nmt   = ws + 4194304;                             // [N,8]        (262,144)
  float* hcent = ws + 4456448;                             // [R,G,4,128]  (131,072)
  float* wcc   = ws + 4587520;                             // [R,G,16]     (4,096)
  unsigned short* aggbb16 = (unsigned short*)(ws + 4591616); // [N,128] bf16 (2,097,152 f)
  int*   order = (int*)(ws + 6688768);                     // [E]          (131,072)
  int*   osrc  = (int*)(ws + 6819840);                     // [E]          (131,072)
  int*   rowst = (int*)(ws + 6950912);                     // [N]          (32,768)
  float* pnum  = ws + 6983680;                             // [8,G,16,128] (2,097,152)
  float* pabc  = ws + 9080832;                             // [8,G,16,128] (2,097,152)
  float* den   = ws + 11177984;                            // [8,G]        (1,024)
  float* gsum  = ws + 11179008;                            // [G,128]      (16,384)
  unsigned int* maxbits = (unsigned int*)(ws + 11195392);  // (64)
  unsigned short* Wbbp = (unsigned short*)(ws + 11195456); // [128,128] bf16 (8,192 f)
  unsigned short* Wsbp = (unsigned short*)(ws + 11203648);
  unsigned short* Wcbp = (unsigned short*)(ws + 11211840);

  hipMemsetAsync(gsum, 0, (16384 + 64) * sizeof(float), stream);

  k_wrep  <<<3*128, 128, 0, stream>>>(Wbb, Wsb, Wcb, Wbbp, Wsbp, Wcbp);
  k_atom  <<<Nn/32, 256, 0, stream>>>(xf, Wa, ba, Wsc, Wb2c, xh, nmt);
  k_csr   <<<Gg,    256, 0, stream>>>(ei, nmt, order, osrc, rowst, den);
  k_gather<<<Gg*16, 256, 0, stream>>>(xh, nmt, ea, We, order, osrc, rowst,
                                      aggbb16, pnum, pabc);
  k_wcc   <<<Gg,    256, 0, stream>>>(nmt, ei, wcc, maxbits);
  k_hcent <<<2*Gg,  128, 0, stream>>>(pnum, den, pabc, wcc, maxbits, Wbc, WccW, Wsc2, hcent);
  k_hbase <<<Nn/64, 256, 0, stream>>>(aggbb16, xh, nmt, hcent, Wbbp, Wsbp, Wcbp, gsum);
  k_out   <<<Gg,    128, 0, stream>>>(gsum, Wint, bint, Wout, bout, (float*)d_out);
}

// Round 8
// 293.257 us; speedup vs baseline: 1.9069x; 1.0480x over previous
//
#include <hip/hip_runtime.h>
#include <hip/hip_bf16.h>

// Problem sizes (fixed)
#define Nn 32768   // nodes
#define Ee 131072  // edges
#define Gg 128     // graphs
#define Dd 128
#define ASTR 1032  // salpha padded stride (breaks bank aliasing)

using bf16 = __hip_bfloat16;
typedef __attribute__((ext_vector_type(8))) short bf16x8;
typedef __attribute__((ext_vector_type(4))) float f32x4;

__device__ __forceinline__ float b2f(bf16 v){ return __bfloat162float(v); }
__device__ __forceinline__ bf16  f2b(float v){ return __float2bfloat16(v); }
__device__ __forceinline__ unsigned short bf16bits(float v){
  union { bf16 b; unsigned short u; } cv; cv.b = f2b(v); return cv.u;
}
__device__ __forceinline__ unsigned int packxh(float xv, float hv){
  return ((unsigned int)bf16bits(hv) << 16) | (unsigned int)bf16bits(xv);
}
__device__ __forceinline__ float upk_x(unsigned int v){ return __uint_as_float(v << 16); }
__device__ __forceinline__ float upk_h(unsigned int v){ return __uint_as_float(v & 0xffff0000u); }

// K0: repack Wbb/Wsb/Wcb fp32 [k][n] -> bf16 transposed [n][k]
__global__ __launch_bounds__(128)
void k_wrep(const float* __restrict__ Wbb, const float* __restrict__ Wsb,
            const float* __restrict__ Wcb, unsigned short* __restrict__ Wbbp,
            unsigned short* __restrict__ Wsbp, unsigned short* __restrict__ Wcbp) {
  int mat = blockIdx.x >> 7, n = blockIdx.x & 127, k = threadIdx.x;
  const float* src = (mat == 0) ? Wbb : (mat == 1) ? Wsb : Wcb;
  unsigned short* dst = (mat == 0) ? Wbbp : (mat == 1) ? Wsbp : Wcbp;
  dst[n*128 + k] = bf16bits(src[k*128 + n]);
}

// K1: x = xf@Wa + ba; nmt[n][rc] = softmax_c(x@Wsc); h = relu(x@Wb2c).
__global__ __launch_bounds__(256)
void k_atom(const float* __restrict__ xf, const float* __restrict__ Wa,
            const float* __restrict__ ba, const float* __restrict__ Wsc,
            const float* __restrict__ Wb2c,
            unsigned int* __restrict__ xh, float* __restrict__ nmt) {
  __shared__ float sxf[32*64];
  __shared__ float sx[32*128];
  __shared__ float ss[32*8];
  __shared__ float sWsc[1024];
  int tid = threadIdx.x, n0 = blockIdx.x * 32;
  int ct = tid & 31, rt = tid >> 5;
  int c0 = ct*4, r0 = rt*4;
  for (int j = tid; j < 2048; j += 256) sxf[j] = xf[n0*64 + j];
  for (int j = tid; j < 1024; j += 256) sWsc[j] = Wsc[j];
  __syncthreads();
  float acc[4][4];
  #pragma unroll
  for (int i = 0; i < 4; ++i)
    #pragma unroll
    for (int j = 0; j < 4; ++j) acc[i][j] = ba[c0+j];
  for (int k = 0; k < 64; ++k) {
    float4 bv = *reinterpret_cast<const float4*>(&Wa[k*128 + c0]);
    #pragma unroll
    for (int i = 0; i < 4; ++i) {
      float a = sxf[(r0+i)*64 + k];
      acc[i][0] += a*bv.x; acc[i][1] += a*bv.y; acc[i][2] += a*bv.z; acc[i][3] += a*bv.w;
    }
  }
  #pragma unroll
  for (int i = 0; i < 4; ++i)
    #pragma unroll
    for (int j = 0; j < 4; ++j) sx[(r0+i)*128 + c0+j] = acc[i][j];
  __syncthreads();
  {
    int node = tid >> 3, col = tid & 7;
    float s = 0.f;
    for (int d = 0; d < 128; ++d) s += sx[node*128 + d] * sWsc[d*8 + col];
    ss[node*8 + col] = s;
  }
  __syncthreads();
  if (tid < 64) {
    int node = tid >> 1, k = tid & 1;
    float v0 = ss[node*8 + 0 + k], v1 = ss[node*8 + 2 + k];
    float v2 = ss[node*8 + 4 + k], v3 = ss[node*8 + 6 + k];
    float mx = fmaxf(fmaxf(v0, v1), fmaxf(v2, v3));
    float e0 = expf(v0-mx), e1 = expf(v1-mx), e2 = expf(v2-mx), e3 = expf(v3-mx);
    float inv = 1.f / (e0+e1+e2+e3);
    size_t nb = (size_t)(n0 + node)*8 + k*4;
    nmt[nb+0] = e0*inv; nmt[nb+1] = e1*inv; nmt[nb+2] = e2*inv; nmt[nb+3] = e3*inv;
  }
  float acc2[4][4];
  #pragma unroll
  for (int i = 0; i < 4; ++i)
    #pragma unroll
    for (int j = 0; j < 4; ++j) acc2[i][j] = 0.f;
  for (int k = 0; k < 128; ++k) {
    float4 bv = *reinterpret_cast<const float4*>(&Wb2c[k*128 + c0]);
    #pragma unroll
    for (int i = 0; i < 4; ++i) {
      float a = sx[(r0+i)*128 + k];
      acc2[i][0] += a*bv.x; acc2[i][1] += a*bv.y; acc2[i][2] += a*bv.z; acc2[i][3] += a*bv.w;
    }
  }
  #pragma unroll
  for (int i = 0; i < 4; ++i)
    #pragma unroll
    for (int j = 0; j < 4; ++j)
      xh[(size_t)(n0+r0+i)*128 + c0+j] = packxh(acc[i][j], fmaxf(acc2[i][j], 0.f));
}

// K2: per-graph dst-CSR (osrc, rowstart) + sea[n,16] = sum of in-edge ea rows
//     + den = per-graph sum of nmt
__global__ __launch_bounds__(256)
void k_csr(const int* __restrict__ ei, const float* __restrict__ nmt,
           const float* __restrict__ ea,
           int* __restrict__ osrc, int* __restrict__ rowstart,
           float* __restrict__ sea, float* __restrict__ den) {
  __shared__ int cnt[256], off[256], sdl[1024], sorder[1024];
  __shared__ float sden[256*8];
  int t = threadIdx.x, g = blockIdx.x;
  cnt[t] = 0;
  __syncthreads();
  #pragma unroll
  for (int j = 0; j < 4; ++j) {
    int e = t + j*256;
    int dl = ei[Ee + g*1024 + e] - g*256;
    sdl[e] = dl;
    atomicAdd(&cnt[dl], 1);
  }
  {
    const float4* p = reinterpret_cast<const float4*>(nmt + (size_t)(g*256 + t)*8);
    float4 a = p[0], b = p[1];
    sden[t*8+0]=a.x; sden[t*8+1]=a.y; sden[t*8+2]=a.z; sden[t*8+3]=a.w;
    sden[t*8+4]=b.x; sden[t*8+5]=b.y; sden[t*8+6]=b.z; sden[t*8+7]=b.w;
  }
  __syncthreads();
  off[t] = cnt[t];
  __syncthreads();
  for (int s = 1; s < 256; s <<= 1) {
    int v = (t >= s) ? off[t - s] : 0;
    __syncthreads();
    off[t] += v;
    __syncthreads();
  }
  int startv = off[t] - cnt[t];
  int mycnt = cnt[t];
  rowstart[g*256 + t] = startv;
  off[t] = startv;
  __syncthreads();
  #pragma unroll
  for (int j = 0; j < 4; ++j) {
    int e = t + j*256;
    int pos = atomicAdd(&off[sdl[e]], 1);
    sorder[pos] = e;
    osrc[g*1024 + pos] = ei[g*1024 + e];
  }
  __syncthreads();
  // sea for node t
  float s0x=0,s0y=0,s0z=0,s0w=0, s1x=0,s1y=0,s1z=0,s1w=0;
  float s2x=0,s2y=0,s2z=0,s2w=0, s3x=0,s3y=0,s3z=0,s3w=0;
  for (int jj = startv; jj < startv + mycnt; ++jj) {
    int e = sorder[jj];
    const float4* er = reinterpret_cast<const float4*>(ea + ((size_t)g*1024 + e)*16);
    float4 a0 = er[0], a1 = er[1], a2 = er[2], a3 = er[3];
    s0x+=a0.x; s0y+=a0.y; s0z+=a0.z; s0w+=a0.w;
    s1x+=a1.x; s1y+=a1.y; s1z+=a1.z; s1w+=a1.w;
    s2x+=a2.x; s2y+=a2.y; s2z+=a2.z; s2w+=a2.w;
    s3x+=a3.x; s3y+=a3.y; s3z+=a3.z; s3w+=a3.w;
  }
  float4* so = reinterpret_cast<float4*>(sea + (size_t)(g*256 + t)*16);
  so[0] = make_float4(s0x,s0y,s0z,s0w);
  so[1] = make_float4(s1x,s1y,s1z,s1w);
  so[2] = make_float4(s2x,s2y,s2z,s2w);
  so[3] = make_float4(s3x,s3y,s3z,s3w);
  if (t < 8) {
    float s = 0.f;
    for (int p = 0; p < 256; ++p) s += sden[p*8 + t];
    den[t*Gg + g] = s;
  }
}

// K3: edge-scalar kernel (block per graph): wcc + maxbits; alpha -> beta (bnm);
//     gea[rc,g,16] = sum_e alpha*ea
__global__ __launch_bounds__(256)
void k_edgesc(const int* __restrict__ ei, const float* __restrict__ nmt,
              const float* __restrict__ ea, float* __restrict__ wcc,
              unsigned int* __restrict__ maxbits, float* __restrict__ bnm,
              float* __restrict__ gea) {
  __shared__ float salpha[8*ASTR];  // 33 KB
  __shared__ float sbeta[8*256];    // 8 KB
  __shared__ float red[20];
  __shared__ float geap[4*128];
  int t = threadIdx.x, g = blockIdx.x;
  for (int j = t; j < 2048; j += 256) sbeta[j] = 0.f;
  if (t < 20) red[t] = 0.f;
  __syncthreads();
  float w[20];
  #pragma unroll
  for (int i = 0; i < 20; ++i) w[i] = 0.f;
  #pragma unroll
  for (int j = 0; j < 4; ++j) {
    int e = t + j*256;
    int s = ei[g*1024 + e], dd = ei[Ee + g*1024 + e];
    const float4* ps4 = reinterpret_cast<const float4*>(nmt + (size_t)s*8);
    const float4* pt4 = reinterpret_cast<const float4*>(nmt + (size_t)dd*8);
    float4 sv0 = ps4[0], sv1 = ps4[1], tv0 = pt4[0], tv1 = pt4[1];
    float ps[8] = {sv0.x,sv0.y,sv0.z,sv0.w,sv1.x,sv1.y,sv1.z,sv1.w};
    float pt[8] = {tv0.x,tv0.y,tv0.z,tv0.w,tv1.x,tv1.y,tv1.z,tv1.w};
    #pragma unroll
    for (int r = 0; r < 2; ++r) {
      int b = r*4;
      w[r*10+0] += ps[b+0]*pt[b+1]; w[r*10+1] += ps[b+0]*pt[b+2]; w[r*10+2] += ps[b+0]*pt[b+3];
      w[r*10+3] += ps[b+1]*pt[b+2]; w[r*10+4] += ps[b+1]*pt[b+3]; w[r*10+5] += ps[b+2]*pt[b+3];
      w[r*10+6] += ps[b+0]*pt[b+0]; w[r*10+7] += ps[b+1]*pt[b+1];
      w[r*10+8] += ps[b+2]*pt[b+2]; w[r*10+9] += ps[b+3]*pt[b+3];
    }
    int sl = s - g*256;
    #pragma unroll
    for (int rc = 0; rc < 8; ++rc) {
      float al = ps[rc]*pt[rc]*pt[rc];
      salpha[rc*ASTR + e] = al;
      atomicAdd(&sbeta[rc*256 + sl], al);
    }
  }
  #pragma unroll
  for (int i = 0; i < 20; ++i) {
    for (int off2 = 32; off2 > 0; off2 >>= 1) w[i] += __shfl_down(w[i], off2);
  }
  if ((t & 63) == 0) {
    #pragma unroll
    for (int i = 0; i < 20; ++i) atomicAdd(&red[i], w[i]);
  }
  __syncthreads();   // salpha, sbeta, red all complete
  if (t < 32) {
    int r = t >> 4, ij = t & 15, i = ij >> 2, j = ij & 3;
    float v;
    if (i == j) v = 0.5f * red[r*10 + 6 + i];
    else { int a = i < j ? i : j, b = i < j ? j : i;
           int p = (a == 0) ? (b - 1) : (a == 1) ? (b + 1) : 5;
           v = red[r*10 + p]; }
    wcc[(r*Gg + g)*16 + ij] = v;
    atomicMax(maxbits, __float_as_uint(v));
  }
  // Phase B: gea
  int wv = t >> 6, l = t & 63;
  int j16 = l & 15, rb = l >> 4;
  float acc0 = 0.f, acc1 = 0.f;
  int ebase = wv*256;
  for (int ee = 0; ee < 256; ++ee) {
    float eav = ea[((size_t)g*1024 + ebase + ee)*16 + j16];
    acc0 += salpha[rb*ASTR + ebase + ee] * eav;
    acc1 += salpha[(rb+4)*ASTR + ebase + ee] * eav;
  }
  geap[wv*128 + l]      = acc0;
  geap[wv*128 + 64 + l] = acc1;
  __syncthreads();
  if (t < 128) {
    float s = geap[t] + geap[128+t] + geap[256+t] + geap[384+t];
    int rc = t >> 4, j = t & 15;
    gea[((size_t)rc*Gg + g)*16 + j] = s;
  }
  // beta writeout [n][8]
  {
    float b0 = sbeta[0*256+t], b1 = sbeta[1*256+t], b2 = sbeta[2*256+t], b3 = sbeta[3*256+t];
    float b4 = sbeta[4*256+t], b5 = sbeta[5*256+t], b6 = sbeta[6*256+t], b7 = sbeta[7*256+t];
    float4* bo = reinterpret_cast<float4*>(bnm + (size_t)(g*256 + t)*8);
    bo[0] = make_float4(b0,b1,b2,b3);
    bo[1] = make_float4(b4,b5,b6,b7);
  }
}

// K4: slim gather. grid (g, 16th)=2048 blocks.
//   aggbb16[n,:] = bf16( sum_{in(n)} x[src] + sea[n]@We )
//   pnum[rc] partial = sum_n (nm+beta)[rc][n]*h[n,:]; pabc = sum_n nm*x
__global__ __launch_bounds__(256)
void k_gather(const unsigned int* __restrict__ xh, const float* __restrict__ nmt,
              const float* __restrict__ bnm, const float* __restrict__ sea,
              const float* __restrict__ We, const int* __restrict__ osrc,
              const int* __restrict__ rowstart,
              unsigned short* __restrict__ aggbb16, float* __restrict__ pnum,
              float* __restrict__ pabc) {
  __shared__ float combN[8*128], combA[8*128];
  int t = threadIdx.x, d = t & 127, q = t >> 7;
  int g = blockIdx.x >> 4, e16 = blockIdx.x & 15;
  int nbase = g*256 + e16*16;
  float w[16];
  #pragma unroll
  for (int j = 0; j < 16; ++j) w[j] = We[j*128 + d];
  float aH[8] = {0,0,0,0,0,0,0,0};
  float aX[8] = {0,0,0,0,0,0,0,0};
  for (int nn = q; nn < 16; nn += 2) {
    int n = nbase + nn;
    unsigned int vn = xh[(size_t)n*128 + d];
    float xn = upk_x(vn), hn = upk_h(vn);
    const float4* pp = reinterpret_cast<const float4*>(nmt + (size_t)n*8);
    float4 p0 = pp[0], p1 = pp[1];
    float pc[8] = {p0.x,p0.y,p0.z,p0.w,p1.x,p1.y,p1.z,p1.w};
    const float4* bp = reinterpret_cast<const float4*>(bnm + (size_t)n*8);
    float4 b0 = bp[0], b1 = bp[1];
    float bt[8] = {b0.x,b0.y,b0.z,b0.w,b1.x,b1.y,b1.z,b1.w};
    #pragma unroll
    for (int rc = 0; rc < 8; ++rc) {
      aH[rc] += (pc[rc] + bt[rc])*hn;
      aX[rc] += pc[rc]*xn;
    }
    const float4* sp = reinterpret_cast<const float4*>(sea + (size_t)n*16);
    float4 s0 = sp[0], s1 = sp[1], s2 = sp[2], s3 = sp[3];
    float agg = s0.x*w[0] + s0.y*w[1] + s0.z*w[2] + s0.w*w[3]
              + s1.x*w[4] + s1.y*w[5] + s1.z*w[6] + s1.w*w[7]
              + s2.x*w[8] + s2.y*w[9] + s2.z*w[10]+ s2.w*w[11]
              + s3.x*w[12]+ s3.y*w[13]+ s3.z*w[14]+ s3.w*w[15];
    int ln = n - g*256;
    int start = rowstart[n];
    int end = (ln == 255) ? 1024 : rowstart[n+1];
    for (int jj = start; jj < end; ++jj) {
      int sg = osrc[g*1024 + jj];
      agg += upk_x(xh[(size_t)sg*128 + d]);
    }
    aggbb16[(size_t)n*128 + d] = bf16bits(agg);
  }
  if (q == 1) {
    #pragma unroll
    for (int rc = 0; rc < 8; ++rc) { combN[rc*128+d] = aH[rc]; combA[rc*128+d] = aX[rc]; }
  }
  __syncthreads();
  if (q == 0) {
    #pragma unroll
    for (int rc = 0; rc < 8; ++rc) {
      pnum[(((size_t)rc*Gg + g)*16 + e16)*128 + d] = aH[rc] + combN[rc*128+d];
      pabc[(((size_t)rc*Gg + g)*16 + e16)*128 + d] = aX[rc] + combA[rc*128+d];
    }
  }
}

// K5: cent_x = (node-part + gea@We)/(den+1e-6);
//     h_cent = relu(abc@Wbc + (Wcc_n@cent)@Wcc + cent@Wsc)
__global__ __launch_bounds__(128)
void k_hcent(const float* __restrict__ pnum, const float* __restrict__ den,
             const float* __restrict__ pabc, const float* __restrict__ gea,
             const float* __restrict__ We, const float* __restrict__ wcc,
             const unsigned int* __restrict__ maxbits,
             const float* __restrict__ Wbc, const float* __restrict__ Wcc_,
             const float* __restrict__ Wsc2, float* __restrict__ hcent) {
  __shared__ float scent[512], sbc[512], sccs[512], swcc[16];
  int tid = threadIdx.x, r = blockIdx.x >> 7, g = blockIdx.x & 127;
  float inv = 1.f / (__uint_as_float(*maxbits) + 1e-9f);
  if (tid < 16) swcc[tid] = wcc[(r*Gg + g)*16 + tid] * inv;
  for (int c = 0; c < 4; ++c) {
    int rc = r*4 + c;
    float nv = 0.f, av = 0.f;
    #pragma unroll
    for (int s = 0; s < 16; ++s) {
      nv += pnum[(((size_t)rc*Gg + g)*16 + s)*128 + tid];
      av += pabc[(((size_t)rc*Gg + g)*16 + s)*128 + tid];
    }
    const float* geag = gea + ((size_t)rc*Gg + g)*16;
    #pragma unroll
    for (int j = 0; j < 16; ++j) nv += geag[j] * We[j*128 + tid];
    float dn = den[rc*Gg + g] + 1e-6f;
    scent[c*128 + tid] = nv / dn;
    sbc[c*128 + tid]   = av;
  }
  __syncthreads();
  for (int i = 0; i < 4; ++i) {
    sccs[i*128 + tid] = swcc[i*4+0]*scent[tid]       + swcc[i*4+1]*scent[128 + tid]
                      + swcc[i*4+2]*scent[256 + tid] + swcc[i*4+3]*scent[384 + tid];
  }
  __syncthreads();
  float acc[4] = {0.f, 0.f, 0.f, 0.f};
  for (int k = 0; k < 128; ++k) {
    float wb = Wbc[k*128 + tid], wc = Wcc_[k*128 + tid], ws2 = Wsc2[k*128 + tid];
    #pragma unroll
    for (int c = 0; c < 4; ++c)
      acc[c] += sbc[c*128 + k]*wb + sccs[c*128 + k]*wc + scent[c*128 + k]*ws2;
  }
  #pragma unroll
  for (int c = 0; c < 4; ++c)
    hcent[((r*Gg + g)*4 + c)*128 + tid] = fmaxf(acc[c], 0.f);
}

// K6 (MFMA): bbsb = aggbb@Wbb + x@Wsb; per r: scb = (nm x hcent);
// h_base = relu(bbsb + scb@Wcb); mean over r; column sums -> gsum.
__global__ __launch_bounds__(256)
void k_hbase(const unsigned short* __restrict__ aggbb16,
             const unsigned int* __restrict__ xh,
             const float* __restrict__ nmt, const float* __restrict__ hcent,
             const unsigned short* __restrict__ Wbbp,
             const unsigned short* __restrict__ Wsbp,
             const unsigned short* __restrict__ Wcbp,
             float* __restrict__ gsum) {
  __shared__ unsigned short A1[64*136];
  __shared__ unsigned short A2[64*136];
  __shared__ float shc[512];
  __shared__ float snm[256];
  __shared__ float pred[128];
  int tid = threadIdx.x, n0 = blockIdx.x*64, g = n0 >> 8;
  int lane = tid & 63, wv = tid >> 6;
  int m = lane & 15, quad = lane >> 4;
  int rbase = wv*16;
  for (int j = tid; j < 1024; j += 256) {
    int row = j >> 4, col = (j & 15) * 8;
    uint4 v = *reinterpret_cast<const uint4*>(aggbb16 + (size_t)(n0+row)*128 + col);
    *reinterpret_cast<uint4*>(&A1[row*136 + col]) = v;
  }
  for (int j = tid; j < 2048; j += 256) {
    int row = j >> 5, col = (j & 31) * 4;
    uint4 v = *reinterpret_cast<const uint4*>(xh + (size_t)(n0+row)*128 + col);
    uint2 o;
    o.x = (v.x & 0xffffu) | (v.y << 16);
    o.y = (v.z & 0xffffu) | (v.w << 16);
    *reinterpret_cast<uint2*>(&A2[row*136 + col]) = o;
  }
  __syncthreads();
  f32x4 bb[8];
  #pragma unroll
  for (int nt = 0; nt < 8; ++nt) bb[nt] = (f32x4){0.f,0.f,0.f,0.f};
  const short* a1r = (const short*)&A1[(rbase + m)*136];
  const short* a2r = (const short*)&A2[(rbase + m)*136];
  #pragma unroll
  for (int nt = 0; nt < 8; ++nt) {
    #pragma unroll
    for (int kk = 0; kk < 4; ++kk) {
      int ko = kk*32 + quad*8;
      bf16x8 av1 = *reinterpret_cast<const bf16x8*>(a1r + ko);
      bf16x8 wv1 = *reinterpret_cast<const bf16x8*>((const short*)Wbbp + (nt*16 + m)*128 + ko);
      bb[nt] = __builtin_amdgcn_mfma_f32_16x16x32_bf16(av1, wv1, bb[nt], 0, 0, 0);
      bf16x8 av2 = *reinterpret_cast<const bf16x8*>(a2r + ko);
      bf16x8 wv2 = *reinterpret_cast<const bf16x8*>((const short*)Wsbp + (nt*16 + m)*128 + ko);
      bb[nt] = __builtin_amdgcn_mfma_f32_16x16x32_bf16(av2, wv2, bb[nt], 0, 0, 0);
    }
  }
  __syncthreads();
  unsigned short* SB = A2;
  f32x4 msum[8];
  #pragma unroll
  for (int nt = 0; nt < 8; ++nt) msum[nt] = (f32x4){0.f,0.f,0.f,0.f};
  for (int r = 0; r < 2; ++r) {
    for (int j = tid; j < 512; j += 256) shc[j] = hcent[((size_t)(r*Gg + g)*4)*128 + j];
    if (tid < 256) snm[tid] = nmt[(size_t)(n0 + (tid >> 2))*8 + r*4 + (tid & 3)];
    __syncthreads();
    for (int j = tid; j < 8192; j += 256) {
      int node = j >> 7, k = j & 127;
      float v = snm[node*4+0]*shc[k]       + snm[node*4+1]*shc[128 + k]
              + snm[node*4+2]*shc[256 + k] + snm[node*4+3]*shc[384 + k];
      SB[node*136 + k] = bf16bits(v);
    }
    __syncthreads();
    f32x4 aw[8];
    #pragma unroll
    for (int nt = 0; nt < 8; ++nt) aw[nt] = (f32x4){0.f,0.f,0.f,0.f};
    const short* sbr = (const short*)&SB[(rbase + m)*136];
    #pragma unroll
    for (int nt = 0; nt < 8; ++nt) {
      #pragma unroll
      for (int kk = 0; kk < 4; ++kk) {
        int ko = kk*32 + quad*8;
        bf16x8 av = *reinterpret_cast<const bf16x8*>(sbr + ko);
        bf16x8 wvv = *reinterpret_cast<const bf16x8*>((const short*)Wcbp + (nt*16 + m)*128 + ko);
        aw[nt] = __builtin_amdgcn_mfma_f32_16x16x32_bf16(av, wvv, aw[nt], 0, 0, 0);
      }
    }
    #pragma unroll
    for (int nt = 0; nt < 8; ++nt) {
      #pragma unroll
      for (int i = 0; i < 4; ++i)
        msum[nt][i] += 0.5f * fmaxf(bb[nt][i] + aw[nt][i], 0.f);
    }
    __syncthreads();
  }
  if (tid < 128) pred[tid] = 0.f;
  __syncthreads();
  #pragma unroll
  for (int nt = 0; nt < 8; ++nt) {
    float s = msum[nt][0] + msum[nt][1] + msum[nt][2] + msum[nt][3];
    atomicAdd(&pred[nt*16 + m], s);
  }
  __syncthreads();
  if (tid < 128) atomicAdd(&gsum[g*128 + tid], pred[tid]);
}

// K7: graph mean + W_inter + W_out head
__global__ __launch_bounds__(128)
void k_out(const float* __restrict__ gsum, const float* __restrict__ Wint,
           const float* __restrict__ bint, const float* __restrict__ Wout,
           const float* __restrict__ bout, float* __restrict__ out) {
  __shared__ float ss[128], sge[128];
  int tid = threadIdx.x, g = blockIdx.x;
  ss[tid] = gsum[g*128 + tid] * (1.f/256.f);
  __syncthreads();
  float ge = bint[tid];
  for (int k = 0; k < 128; ++k) ge += ss[k] * Wint[k*128 + tid];
  sge[tid] = ge;
  __syncthreads();
  if (tid < 10) {
    float o = bout[tid];
    for (int d = 0; d < 128; ++d) o += sge[d] * Wout[d*10 + tid];
    out[g*10 + tid] = o;
  }
}

extern "C" void kernel_launch(void* const* d_in, const int* in_sizes, int n_in,
                              void* d_out, int out_size, void* d_ws, size_t ws_size,
                              hipStream_t stream) {
  const float* xf   = (const float*)d_in[0];
  const float* ea   = (const float*)d_in[1];
  const float* Wa   = (const float*)d_in[2];
  const float* ba   = (const float*)d_in[3];
  const float* Wsc  = (const float*)d_in[4];
  const float* We   = (const float*)d_in[5];
  const float* Wb2c = (const float*)d_in[6];
  const float* Wbb  = (const float*)d_in[7];
  const float* Wbc  = (const float*)d_in[8];
  const float* Wcb  = (const float*)d_in[9];
  const float* WccW = (const float*)d_in[10];
  const float* Wsb  = (const float*)d_in[11];
  const float* Wsc2 = (const float*)d_in[12];
  const float* Wint = (const float*)d_in[13];
  const float* bint = (const float*)d_in[14];
  const float* Wout = (const float*)d_in[15];
  const float* bout = (const float*)d_in[16];
  const int*   ei   = (const int*)d_in[17];

  // Workspace layout (float offsets); total 11,891,776 f = 47.6 MB
  float* ws    = (float*)d_ws;
  unsigned int* xh = (unsigned int*)ws;                      // [N,128]      @0
  float* nmt   = ws + 4194304;                               // [N,8]
  float* hcent = ws + 4456448;                               // [R,G,4,128]
  float* wcc   = ws + 4587520;                               // [R,G,16]
  unsigned short* aggbb16 = (unsigned short*)(ws + 4591616); // [N,128] bf16
  int*   osrc  = (int*)(ws + 6688768);                       // [E]
  int*   rowst = (int*)(ws + 6819840);                       // [N]
  float* sea   = ws + 6852608;                               // [N,16]
  float* bnm   = ws + 7376896;                               // [N,8]
  float* gea   = ws + 7639040;                               // [8,G,16]
  float* pnum  = ws + 7655424;                               // [8,G,16,128]
  float* pabc  = ws + 9752576;                               // [8,G,16,128]
  float* den   = ws + 11849728;                              // [8,G]
  float* gsum  = ws + 11850752;                              // [G,128]
  unsigned int* maxbits = (unsigned int*)(ws + 11867136);    // (64)
  unsigned short* Wbbp = (unsigned short*)(ws + 11867200);   // [128,128] bf16
  unsigned short* Wsbp = (unsigned short*)(ws + 11875392);
  unsigned short* Wcbp = (unsigned short*)(ws + 11883584);

  hipMemsetAsync(gsum, 0, (16384 + 64) * sizeof(float), stream);

  k_wrep  <<<3*128, 128, 0, stream>>>(Wbb, Wsb, Wcb, Wbbp, Wsbp, Wcbp);
  k_atom  <<<Nn/32, 256, 0, stream>>>(xf, Wa, ba, Wsc, Wb2c, xh, nmt);
  k_csr   <<<Gg,    256, 0, stream>>>(ei, nmt, ea, osrc, rowst, sea, den);
  k_edgesc<<<Gg,    256, 0, stream>>>(ei, nmt, ea, wcc, maxbits, bnm, gea);
  k_gather<<<Gg*16, 256, 0, stream>>>(xh, nmt, bnm, sea, We, osrc, rowst,
                                      aggbb16, pnum, pabc);
  k_hcent <<<2*Gg,  128, 0, stream>>>(pnum, den, pabc, gea, We, wcc, maxbits,
                                      Wbc, WccW, Wsc2, hcent);
  k_hbase <<<Nn/64, 256, 0, stream>>>(aggbb16, xh, nmt, hcent, Wbbp, Wsbp, Wcbp, gsum);
  k_out   <<<Gg,    128, 0, stream>>>(gsum, Wint, bint, Wout, bout, (float*)d_out);
}